// Round 4
// baseline (1142.758 us; speedup 1.0000x reference)
//
#include <hip/hip_runtime.h>
#include <cmath>

#define NT 256
#define S1NT 128
#define S2NT 128
#define BT 128

// ---------------- ws float-offsets for constant tables ----------------
#define OFF_W60   0          // 19*60 complex
#define OFF_E20   2280       // legacy
#define OFF_E12   2320       // legacy
#define OFF_W2J   2344       // 12 floats
#define OFF_DM1   2356       // 100*60
#define OFF_Y1B   8356       // 100*24 complex
#define OFF_D1R   13156      // [j=20][flat=1330] (2l+1)*d^l at beta1
#define OFF_DM2   39756      // [j=20][k2=286]  w1[j]*d^l(beta1_j)
#define OFF_Y2B   45476      // 286*192 complex
#define OFF_D2R   155300     // [j=12][flat=286] (2l+1)*d^l at beta2
#define OFF_T19U  158732     // 20x19 complex [c][n] e^{+2pi i n c/20}
#define OFF_T11V  159492     // 11x20 complex [r][c] e^{-2pi i (r-5) c/20}
#define OFF_T12U  159932     // 12x11 complex [c][n] e^{+2pi i n c/12}
#define OFF_TABA  160196     // 1330 int packed (l | mi<<8 | ni<<16)
#define OFF_TABB  161526     // 286 int packed
#define OFF_SORD  161812     // 361 int: S items sorted by lmin
#define OFF_END   162176     // 16B aligned
#define N_INIT    102957

__constant__ int c_ZB1[10] = {0,1,10,35,84,165,286,455,680,969};
__constant__ int c_ZB2[6]  = {0,1,10,35,84,165};
__constant__ int c_BOFF[6] = {0,22,208,718,1712,3350};  // padded row offsets for k_Z2 LDS

// wave-local sync (per-wave-private LDS phase buffers only)
__device__ inline void wsync() {
    __asm__ volatile("" ::: "memory");
    __builtin_amdgcn_s_waitcnt(0xC07F);   // vmcnt=63, expcnt=7, lgkmcnt=0
    __builtin_amdgcn_wave_barrier();
    __asm__ volatile("" ::: "memory");
}

// ---------------- fp64 helpers for the init kernel ----------------
__device__ inline double dipow(double x, int e) {
    double r = 1.0;
    for (int i = 0; i < e; ++i) r *= x;
    return r;
}

__device__ double wigd(const double* F, const double* Fi, int l, int mp, int m, double beta) {
    double cb = cos(beta * 0.5), sb = sin(beta * 0.5);
    int smin = m - mp; if (smin < 0) smin = 0;
    int smax = l + m;  if (l - mp < smax) smax = l - mp;
    double pref = sqrt(F[l+mp] * F[l-mp] * F[l+m] * F[l-m]);
    double sum = 0.0;
    for (int s = smin; s <= smax; ++s) {
        double t = pref * (Fi[l+m-s] * Fi[s] * Fi[mp-m+s] * Fi[l-mp-s]);
        t *= dipow(cb, 2*l + m - mp - 2*s) * dipow(sb, mp - m + 2*s);
        sum += ((mp - m + s) & 1) ? -t : t;
    }
    return sum;
}

__device__ double qwj(int bnd, int j) {
    const double PI = 3.14159265358979323846;
    double theta = PI * (2*j + 1) / (4.0 * bnd);
    double s = 0.0;
    for (int k = 0; k < bnd; ++k) s += sin(theta * (2*k + 1)) / (2*k + 1);
    return 2.0 / bnd * sin(theta) * s;
}

// ---------------- init ----------------
__global__ void k_init(float* __restrict__ ws) {
    int idx = blockIdx.x * blockDim.x + threadIdx.x;
    if (idx >= N_INIT) return;
    double F[20], Fi[20];
    F[0] = 1.0;
    #pragma unroll
    for (int i = 1; i < 20; ++i) F[i] = F[i-1] * i;
    Fi[19] = 1.0 / F[19];
    #pragma unroll
    for (int i = 18; i >= 0; --i) Fi[i] = Fi[i+1] * (i+1);
    const double PI = 3.14159265358979323846;

    if (idx < 1140) {                       // W60
        int r = idx / 60, a = idx % 60;
        double ang = -2.0 * PI * (double)((r - 9) * a) / 60.0;
        ws[OFF_W60 + 2*idx]     = (float)cos(ang);
        ws[OFF_W60 + 2*idx + 1] = (float)sin(ang);
    } else if (idx < 1160) {
        int t = idx - 1140;
        double ang = 2.0 * PI * t / 20.0;
        ws[OFF_E20 + 2*t]     = (float)cos(ang);
        ws[OFF_E20 + 2*t + 1] = (float)sin(ang);
    } else if (idx < 1172) {
        int t = idx - 1160;
        double ang = 2.0 * PI * t / 12.0;
        ws[OFF_E12 + 2*t]     = (float)cos(ang);
        ws[OFF_E12 + 2*t + 1] = (float)sin(ang);
    } else if (idx < 1184) {                // W2J
        int j = idx - 1172;
        ws[OFF_W2J + j] = (float)qwj(6, j);
    } else if (idx < 7184) {                // DM1[k][j]
        int e = idx - 1184; int k = e / 60, j = e % 60;
        int l = 0; while ((l + 1) * (l + 1) <= k) ++l;
        int m = k - l*l - l;
        double beta = PI * (2*j + 1) / 120.0;
        ws[OFF_DM1 + e] = (float)(qwj(30, j) * wigd(F, Fi, l, m, 0, beta));
    } else if (idx < 9584) {                // Y1B
        int e = idx - 7184; int k = e / 24, g = e % 24;
        int l = 0; while ((l + 1) * (l + 1) <= k) ++l;
        int m = k - l*l - l;
        int bi = g / 8, ai = g % 8;
        double beta  = (bi + 1) * (PI / 8.0) / 3.0;
        double alpha = 2.0 * PI * ai / 8.0;
        double d = wigd(F, Fi, l, m, 0, beta);
        double ph = -(double)m * alpha;
        ws[OFF_Y1B + 2*e]     = (float)(d * cos(ph));
        ws[OFF_Y1B + 2*e + 1] = (float)(d * sin(ph));
    } else if (idx < 36184) {               // D1R [j][flat], prescaled by (2l+1)
        int e = idx - 9584; int j = e / 1330, t = e % 1330;
        int l = 0; while (l < 9 && t >= c_ZB1[l+1]) ++l;
        int L = 2*l + 1, loc = t - c_ZB1[l];
        int mi = loc / L, ni = loc % L;
        double beta = PI * (2*j + 1) / 40.0;
        ws[OFF_D1R + e] = (float)((double)L * wigd(F, Fi, l, mi - l, ni - l, beta));
    } else if (idx < 41904) {               // DM2 [j][k2]
        int e = idx - 36184; int j = e / 286, k2 = e % 286;
        int l = 0; while (l < 5 && k2 >= c_ZB2[l+1]) ++l;
        int L = 2*l + 1, loc = k2 - c_ZB2[l];
        int mi = loc / L, ni = loc % L;
        double beta = PI * (2*j + 1) / 40.0;
        ws[OFF_DM2 + e] = (float)(qwj(10, j) * wigd(F, Fi, l, mi - l, ni - l, beta));
    } else if (idx < 96816) {               // Y2B
        int e = idx - 41904; int k2 = e / 192, g = e % 192;
        int l = 0; while (l < 5 && k2 >= c_ZB2[l+1]) ++l;
        int L = 2*l + 1, loc = k2 - c_ZB2[l];
        int m = loc / L - l, n = loc % L - l;
        int bi = g / 64, ai = (g / 8) % 8, ci = g % 8;
        double beta  = (bi + 1) * (PI / 8.0) / 3.0;
        double alpha = 2.0 * PI * ai / 8.0;
        double gamma = (-2.0 * PI + ci * (PI / 2.0)) - alpha;
        double d = wigd(F, Fi, l, m, n, beta);
        double ph = -((double)m * alpha + (double)n * gamma);
        ws[OFF_Y2B + 2*e]     = (float)(d * cos(ph));
        ws[OFF_Y2B + 2*e + 1] = (float)(d * sin(ph));
    } else if (idx < 100248) {              // D2R [j][flat], prescaled by (2l+1)
        int e = idx - 96816; int j = e / 286, t = e % 286;
        int l = 0; while (l < 5 && t >= c_ZB2[l+1]) ++l;
        int L = 2*l + 1, loc = t - c_ZB2[l];
        int mi = loc / L, ni = loc % L;
        double beta = PI * (2*j + 1) / 24.0;
        ws[OFF_D2R + e] = (float)((double)L * wigd(F, Fi, l, mi - l, ni - l, beta));
    } else if (idx < 100628) {              // T19U [c][n]
        int e = idx - 100248; int c = e / 19, n = e % 19 - 9;
        double ang = 2.0 * PI * (double)(n * c) / 20.0;
        ws[OFF_T19U + 2*e]     = (float)cos(ang);
        ws[OFF_T19U + 2*e + 1] = (float)sin(ang);
    } else if (idx < 100848) {              // T11V [r][c]
        int e = idx - 100628; int r = e / 20, c = e % 20;
        double ang = -2.0 * PI * (double)((r - 5) * c) / 20.0;
        ws[OFF_T11V + 2*e]     = (float)cos(ang);
        ws[OFF_T11V + 2*e + 1] = (float)sin(ang);
    } else if (idx < 100980) {              // T12U [c][n]
        int e = idx - 100848; int c = e / 11, n = e % 11 - 5;
        double ang = 2.0 * PI * (double)(n * c) / 12.0;
        ws[OFF_T12U + 2*e]     = (float)cos(ang);
        ws[OFF_T12U + 2*e + 1] = (float)sin(ang);
    } else if (idx < 102310) {              // TABA
        int t = idx - 100980;
        int l = 0; while (l < 9 && t >= c_ZB1[l+1]) ++l;
        int L = 2*l + 1, loc = t - c_ZB1[l];
        ((int*)ws)[OFF_TABA + t] = l | ((loc / L) << 8) | ((loc % L) << 16);
    } else if (idx < 102596) {              // TABB
        int t = idx - 102310;
        int l = 0; while (l < 5 && t >= c_ZB2[l+1]) ++l;
        int L = 2*l + 1, loc = t - c_ZB2[l];
        ((int*)ws)[OFF_TABB + t] = l | ((loc / L) << 8) | ((loc % L) << 16);
    } else {                                // SORD: S items sorted by lmin
        int t = idx - 102596;                // my item
        int mi = t / 19, ni = t % 19;
        int m = mi - 9, n = ni - 9;
        int am = m < 0 ? -m : m, an = n < 0 ? -n : n;
        int lm = am > an ? am : an;
        int rank = 0;
        for (int t2 = 0; t2 < 361; ++t2) {
            int mi2 = t2 / 19, ni2 = t2 % 19;
            int m2 = mi2 - 9, n2 = ni2 - 9;
            int am2 = m2 < 0 ? -m2 : m2, an2 = n2 < 0 ? -n2 : n2;
            int lm2 = am2 > an2 ? am2 : an2;
            if (lm2 < lm || (lm2 == lm && t2 < t)) ++rank;
        }
        ((int*)ws)[OFF_SORD + rank] = t;
    }
}

// ---------------- small pipeline kernels ----------------
__global__ void k_dft_alpha(const float* __restrict__ x, const float2* __restrict__ W60,
                            float2* __restrict__ xh) {
    int idx = blockIdx.x * blockDim.x + threadIdx.x;
    if (idx >= BT * 60 * 19) return;
    int r = idx % 19;
    int j = (idx / 19) % 60;
    int b = idx / (19 * 60);
    const float* xr = x + (b * 60 + j) * 60;
    const float2* wr = W60 + r * 60;
    float re = 0.f, im = 0.f;
    for (int a = 0; a < 60; ++a) {
        float v = xr[a];
        float2 w = wr[a];
        re += v * w.x; im += v * w.y;
    }
    xh[idx] = make_float2(re * (1.f / 60.f), im * (1.f / 60.f));
}

__global__ void k_X1(const float2* __restrict__ xh, const float* __restrict__ DM1,
                     float2* __restrict__ X) {
    int idx = blockIdx.x * blockDim.x + threadIdx.x;
    if (idx >= 100 * BT) return;
    int b = idx % BT, k = idx / BT;
    int l = 0; while ((l + 1) * (l + 1) <= k) ++l;
    int r = (k - l*l - l) + 9;
    float re = 0.f, im = 0.f;
    for (int j = 0; j < 60; ++j) {
        float d = DM1[k * 60 + j];
        float2 v = xh[(b * 60 + j) * 19 + r];
        re += d * v.x; im += d * v.y;
    }
    X[k * BT + b] = make_float2(re, im);
}

__global__ void k_Yk1(const float* __restrict__ k1, const float2* __restrict__ Y1B,
                      float2* __restrict__ Yk1) {
    int idx = blockIdx.x * blockDim.x + threadIdx.x;
    if (idx >= 100 * 20) return;
    int o = idx % 20, k = idx / 20;
    float re = 0.f, im = 0.f;
    for (int g = 0; g < 24; ++g) {
        float2 y = Y1B[k * 24 + g];
        float w = k1[o * 24 + g];
        re += y.x * w; im += y.y * w;
    }
    const float SC1 = 0.20412414523193154f;  // 1/sqrt(24)
    Yk1[idx] = make_float2(re * SC1, im * SC1);
}

// Yk2 layout: [o][k2][i]; one block per k2, Y2B row staged in LDS
__global__ __launch_bounds__(NT) void k_Yk2(const float* __restrict__ k2in,
                                            const float2* __restrict__ Y2B,
                                            float2* __restrict__ Yk2) {
    const int k = blockIdx.x;      // 0..285
    const int tid = threadIdx.x;
    __shared__ __align__(16) float2 sY[192];
    for (int t = tid; t < 192; t += NT) sY[t] = Y2B[k * 192 + t];
    __syncthreads();
    const float4* sY4 = (const float4*)sY;
    const float SC2 = 0.016137430609197573f; // 1/sqrt(192*20)
    for (int t = tid; t < 800; t += NT) {
        int o = t / 20, i = t % 20;
        const float4* kp = (const float4*)(k2in + (i * 40 + o) * 192);
        float re = 0.f, im = 0.f;
        #pragma unroll 4
        for (int p = 0; p < 48; ++p) {
            float4 w = kp[p];
            float4 y01 = sY4[2*p], y23 = sY4[2*p + 1];
            re += w.x * y01.x + w.y * y01.z + w.z * y23.x + w.w * y23.z;
            im += w.x * y01.y + w.y * y01.w + w.z * y23.y + w.w * y23.w;
        }
        Yk2[(o * 286 + k) * 20 + i] = make_float2(re * SC2, im * SC2);
    }
}

// ---------------- stage 1: block=(b,f); 2 waves x 3 groups of 20 lanes ----------------
// group owns j = gg + 6*pass; lane = output row; twiddles+x1+X2 in registers;
// inputs read via same-address LDS broadcast (free); group buffers bank-staggered.
__global__ __launch_bounds__(S1NT) void k_stage1(
    const float2* __restrict__ X, const float2* __restrict__ Yk1,
    const float* __restrict__ gD1R, const float* __restrict__ gDM2,
    const float2* __restrict__ gT19, const float2* __restrict__ gT11,
    const int* __restrict__ gTABA, const int* __restrict__ gTABB,
    const int* __restrict__ gSORD, float2* __restrict__ X2g) {
    const int b = blockIdx.x % BT;
    const int f = blockIdx.x / BT;   // 0..19
    const int tid = threadIdx.x;
    const int wv = tid >> 6, lane = tid & 63;
    const int grp = lane / 20;       // 0..2 active, 3 idle
    const int lig = lane % 20;
    const int gg  = wv * 3 + grp;    // 0..5
    const int gsafe = (grp < 3) ? gg : 0;

    __shared__ __align__(16) float2 sZ[1330];
    __shared__ __align__(16) float2 sT11[220];    // [n][c] stride 20
    __shared__ __align__(16) float2 sX2[286];
    __shared__ __align__(16) float2 sA[6][372];   // S(361) / G(121); stride 372 -> +8 banks/group
    __shared__ __align__(16) float2 sB[6][388];   // U(380, stride 20) / V(11 rows stride 21)

    for (int t = tid; t < 1330; t += S1NT) {
        int p = gTABA[t];
        int l = p & 255, mi = (p >> 8) & 255, ni = p >> 16;
        float2 a = X[(l*l + mi) * BT + b];
        float2 y = Yk1[(l*l + ni) * 20 + f];
        sZ[t] = make_float2(a.x * y.x + a.y * y.y, a.y * y.x - a.x * y.y);
    }
    for (int t = tid; t < 220; t += S1NT) sT11[t] = gT11[t];
    for (int t = tid; t < 286; t += S1NT) sX2[t] = make_float2(0.f, 0.f);
    __syncthreads();

    // per-lane constant registers
    float2 t19[19];
    #pragma unroll
    for (int n = 0; n < 19; ++n) t19[n] = gT19[lig * 19 + n];
    int sreg[19];
    #pragma unroll
    for (int ii = 0; ii < 19; ++ii) {
        int r = lig + 20 * ii;
        sreg[ii] = (r < 361) ? gSORD[r] : -1;
    }
    float2 x2acc[15];
    int gidx[15];
    #pragma unroll
    for (int i = 0; i < 15; ++i) {
        x2acc[i] = make_float2(0.f, 0.f);
        int k2 = lig + 20 * i;
        if (k2 < 286) {
            int pp = gTABB[k2];
            int l = pp & 255, mi = (pp >> 8) & 255, ni = pp >> 16;
            gidx[i] = (mi - l + 5) * 11 + (ni - l + 5);
        } else gidx[i] = 0;
    }

    float2* S = sA[gsafe];
    float2* U = sB[gsafe];
    float2* V = sB[gsafe];
    float2* G = sA[gsafe];
    float x1r[20];

    for (int pass = 0; pass < 4; ++pass) {
        const int j = gg + 6 * pass;
        const bool act = (grp < 3) && (j < 20);

        // ---- S[t] = sum_l (2l+1) d^l_j Z  (lmin-sorted items)
        if (act) {
            const float* dp = gD1R + j * 1330;
            for (int ii = 0; ii < 19; ++ii) {
                int t = sreg[ii];
                if (t >= 0) {
                    int mi = t / 19, ni = t % 19;
                    int m = mi - 9, n = ni - 9;
                    int am = m < 0 ? -m : m, an = n < 0 ? -n : n;
                    int lmin = am > an ? am : an;
                    float re = 0.f, im = 0.f;
                    for (int l = lmin; l < 10; ++l) {
                        int L = 2*l + 1;
                        int o = c_ZB1[l] + (m + l) * L + (n + l);
                        float dv = dp[o];
                        float2 z = sZ[o];
                        re += dv * z.x; im += dv * z.y;
                    }
                    S[t] = make_float2(re, im);
                }
            }
        }
        wsync();

        // ---- U[m][c=lig] = sum_n S[m][n] t19[n]   (S rows broadcast)
        if (act) {
            for (int m = 0; m < 19; ++m) {
                const float2* Srow = S + m * 19;
                float r0 = 0.f, i0 = 0.f, r1 = 0.f, i1 = 0.f;
                #pragma unroll
                for (int n = 0; n < 18; n += 2) {
                    float2 s = Srow[n],  w = t19[n];
                    r0 += s.x * w.x - s.y * w.y; i0 += s.x * w.y + s.y * w.x;
                    float2 s2 = Srow[n+1], w2 = t19[n+1];
                    r1 += s2.x * w2.x - s2.y * w2.y; i1 += s2.x * w2.y + s2.y * w2.x;
                }
                float2 s = Srow[18], w = t19[18];
                r0 += s.x * w.x - s.y * w.y; i0 += s.x * w.y + s.y * w.x;
                U[m * 20 + lig] = make_float2(r0 + r1, i0 + i1);
            }
        }
        wsync();

        // ---- x1[a=lig][c] = relu(Re sum_m U[m][c] t19[m])  (U broadcast; x1 in regs)
        if (act) {
            for (int c = 0; c < 20; ++c) {
                float a0 = 0.f, a1 = 0.f;
                #pragma unroll
                for (int m = 0; m < 18; m += 2) {
                    float2 u = U[m * 20 + c],      w = t19[m];
                    a0 += u.x * w.x - u.y * w.y;
                    float2 u2 = U[(m+1) * 20 + c], w2 = t19[m+1];
                    a1 += u2.x * w2.x - u2.y * w2.y;
                }
                float2 u = U[18 * 20 + c], w = t19[18];
                a0 += u.x * w.x - u.y * w.y;
                float v = a0 + a1;
                x1r[c] = v > 0.f ? v : 0.f;
            }
        }
        wsync();

        // ---- V[n][a=lig] = sum_c x1r[c] T11[n][c]  (T11 rows broadcast)
        if (act) {
            for (int n = 0; n < 11; ++n) {
                const float2* Tr = sT11 + n * 20;
                float r0 = 0.f, i0 = 0.f, r1 = 0.f, i1 = 0.f;
                #pragma unroll
                for (int c = 0; c < 20; c += 2) {
                    float2 w = Tr[c];
                    r0 += x1r[c] * w.x; i0 += x1r[c] * w.y;
                    float2 w2 = Tr[c+1];
                    r1 += x1r[c+1] * w2.x; i1 += x1r[c+1] * w2.y;
                }
                V[n * 21 + lig] = make_float2(r0 + r1, i0 + i1);
            }
        }
        wsync();

        // ---- G[m][n] = sum_a V[n-row][a] T11[m][a]; lanes 0..21: n=lig%11, half m-range
        if (act && lig < 22) {
            int n = lig % 11, half = lig / 11;
            float2 vcol[20];
            #pragma unroll
            for (int a = 0; a < 20; ++a) vcol[a] = V[n * 21 + a];
            int m0 = half ? 6 : 0, m1 = half ? 11 : 6;
            for (int m = m0; m < m1; ++m) {
                const float2* Tr = sT11 + m * 20;
                float r0 = 0.f, i0 = 0.f, r1 = 0.f, i1 = 0.f;
                #pragma unroll
                for (int a = 0; a < 20; a += 2) {
                    float2 w = Tr[a], v = vcol[a];
                    r0 += v.x * w.x - v.y * w.y; i0 += v.x * w.y + v.y * w.x;
                    float2 w2 = Tr[a+1], v2 = vcol[a+1];
                    r1 += v2.x * w2.x - v2.y * w2.y; i1 += v2.x * w2.y + v2.y * w2.x;
                }
                G[m * 11 + n] = make_float2(r0 + r1, i0 + i1);
            }
        }
        wsync();

        // ---- X2 reg-accumulate: x2acc[i] += DM2[j][k2] * G[gidx]
        if (act) {
            const float* dmp = gDM2 + j * 286;
            #pragma unroll
            for (int i = 0; i < 15; ++i) {
                int k2 = lig + 20 * i;
                if (k2 < 286) {
                    float dm = dmp[k2];
                    float2 g = G[gidx[i]];
                    x2acc[i].x += dm * g.x;
                    x2acc[i].y += dm * g.y;
                }
            }
        }
        wsync();
    }

    // combine 6 groups
    if (grp < 3) {
        #pragma unroll
        for (int i = 0; i < 15; ++i) {
            int k2 = lig + 20 * i;
            if (k2 < 286) {
                atomicAdd(&sX2[k2].x, x2acc[i].x);
                atomicAdd(&sX2[k2].y, x2acc[i].y);
            }
        }
    }
    __syncthreads();
    for (int t = tid; t < 286; t += S1NT) {
        float2 v = sX2[t];
        X2g[b * 5720 + t * 20 + f] = make_float2(v.x * (1.f / 400.f), v.y * (1.f / 400.f));
    }
}

// ---------------- stage 2a: Z[b][o][k2] = sum_{k,i} A . conj(B) ----------------
__global__ __launch_bounds__(NT) void k_Z2(
    const float2* __restrict__ X2g, const float2* __restrict__ Yk2,
    const int* __restrict__ gTABB, float2* __restrict__ Z2g) {
    const int bt = blockIdx.x & 7;        // 0..7
    const int o  = blockIdx.x >> 3;       // 0..39
    const int b0 = bt * 16;
    const int tid = threadIdx.x;

    __shared__ __align__(16) float2 sB[5792];

    const float2* Bg = Yk2 + o * 5720;
    for (int e = tid; e < 5720; e += NT) {
        int k2 = e / 20, i = e % 20;
        int p = gTABB[k2];
        int l = p & 255, r = (p >> 8) & 255, kk = p >> 16;
        sB[c_BOFF[l] + r * (40 * l + 22) + kk * 20 + i] = Bg[e];
    }
    __syncthreads();

    for (int q = tid; q < 16 * 286; q += NT) {
        int b_local = q / 286, t = q % 286;
        int p = gTABB[t];
        int l = p & 255, mi = (p >> 8) & 255, ni = p >> 16;
        int L = 2 * l + 1;
        const float4* ap = (const float4*)(X2g + (size_t)(b0 + b_local) * 5720
                                           + (c_ZB2[l] + mi * L) * 20);
        const float4* bp = (const float4*)(sB + c_BOFF[l] + ni * (40 * l + 22));
        float re = 0.f, im = 0.f;
        int n4 = 10 * L;
        for (int p4 = 0; p4 < n4; ++p4) {
            float4 a = ap[p4], y = bp[p4];
            re += a.x * y.x + a.y * y.y + a.z * y.z + a.w * y.w;
            im += a.y * y.x - a.x * y.y + a.w * y.z - a.z * y.w;
        }
        Z2g[((size_t)(b0 + b_local) * 40 + o) * 286 + t] = make_float2(re, im);
    }
}

// ---------------- stage 2b: per (b,o): j-loop + integrate (2 waves, wave-owned j) ----------------
__global__ __launch_bounds__(S2NT) void k_stage2b(
    const float2* __restrict__ Z2g, const float* __restrict__ gD2R,
    const float2* __restrict__ gT12, const float* __restrict__ gW2J,
    float* __restrict__ feat) {
    const int b = blockIdx.x % BT;
    const int o = blockIdx.x / BT;   // 0..39
    const int tid = threadIdx.x;
    const int wv = tid >> 6, lane = tid & 63;

    __shared__ __align__(16) float2 sZb[286];
    __shared__ __align__(16) float2 sT12[168];   // [c][n], stride 14
    __shared__ __align__(16) float2 sS[2][154];  // [mi][ni], stride 14
    __shared__ __align__(16) float2 sU[2][168];  // [c][mi], stride 14
    __shared__ float sredw[2];

    const float2* Zr = Z2g + ((size_t)b * 40 + o) * 286;
    for (int t = tid; t < 286; t += S2NT) sZb[t] = Zr[t];
    for (int t = tid; t < 132; t += S2NT) sT12[(t / 11) * 14 + (t % 11)] = gT12[t];
    __syncthreads();

    float2* S = sS[wv];
    float2* U = sU[wv];
    float facc = 0.f;

    for (int jj = 0; jj < 6; ++jj) {
        const int j = wv + 2 * jj;

        {
            const float* dp = gD2R + j * 286;
            for (int t = lane; t < 121; t += 64) {
                int mi = t / 11, ni = t % 11;
                int m = mi - 5, n = ni - 5;
                int am = m < 0 ? -m : m, an = n < 0 ? -n : n;
                int lmin = am > an ? am : an;
                float re = 0.f, im = 0.f;
                for (int l = lmin; l < 6; ++l) {
                    int L = 2*l + 1;
                    int off = c_ZB2[l] + (m + l) * L + (n + l);
                    float dv = dp[off];
                    float2 z = sZb[off];
                    re += dv * z.x; im += dv * z.y;
                }
                S[mi * 14 + ni] = make_float2(re, im);
            }
        }
        wsync();

        for (int t = lane; t < 132; t += 64) {
            int mi = t / 12, c = t % 12;
            const float4* sp = (const float4*)(S + mi * 14);
            const float4* tp = (const float4*)(sT12 + c * 14);
            float re = 0.f, im = 0.f;
            #pragma unroll
            for (int p = 0; p < 5; ++p) {
                float4 s = sp[p], w = tp[p];
                re += s.x * w.x - s.y * w.y + s.z * w.z - s.w * w.w;
                im += s.x * w.y + s.y * w.x + s.z * w.w + s.w * w.z;
            }
            float2 s1 = S[mi * 14 + 10], w1 = sT12[c * 14 + 10];
            re += s1.x * w1.x - s1.y * w1.y;
            im += s1.x * w1.y + s1.y * w1.x;
            U[c * 14 + mi] = make_float2(re, im);
        }
        wsync();

        {
            float wj = gW2J[j];
            for (int t = lane; t < 144; t += 64) {
                int a = t / 12, c = t % 12;
                const float4* up = (const float4*)(U + c * 14);
                const float4* tp = (const float4*)(sT12 + a * 14);
                float acc = 0.f;
                #pragma unroll
                for (int p = 0; p < 5; ++p) {
                    float4 u = up[p], w = tp[p];
                    acc += u.x * w.x - u.y * w.y + u.z * w.z - u.w * w.w;
                }
                float2 u1 = U[c * 14 + 10], w1 = sT12[a * 14 + 10];
                acc += u1.x * w1.x - u1.y * w1.y;
                if (acc > 0.f) facc += wj * acc;
            }
        }
        wsync();
    }

    #pragma unroll
    for (int d = 32; d > 0; d >>= 1) facc += __shfl_down(facc, d, 64);
    if (lane == 0) sredw[wv] = facc;
    __syncthreads();
    if (tid == 0) {
        const float INTEG = 0.27415567780803774f;  // (2*pi/12)^2
        feat[b * 40 + o] = (sredw[0] + sredw[1]) * INTEG;
    }
}

__global__ void k_out(const float* __restrict__ feat, const float* __restrict__ w,
                      const float* __restrict__ bias, float* __restrict__ out) {
    int idx = blockIdx.x * blockDim.x + threadIdx.x;
    if (idx >= BT * 10) return;
    int fo = idx % 10, b = idx / 10;
    float acc = bias[fo];
    for (int o2 = 0; o2 < 40; ++o2) acc += feat[b * 40 + o2] * w[fo * 40 + o2];
    out[idx] = acc;
}

extern "C" void kernel_launch(void* const* d_in, const int* in_sizes, int n_in,
                              void* d_out, int out_size, void* d_ws, size_t ws_size,
                              hipStream_t stream) {
    (void)in_sizes; (void)n_in; (void)out_size; (void)ws_size;
    const float* x   = (const float*)d_in[0];
    const float* k1  = (const float*)d_in[1];
    const float* k2  = (const float*)d_in[2];
    const float* wO  = (const float*)d_in[3];
    const float* bO  = (const float*)d_in[4];
    float* out = (float*)d_out;

    float* ws = (float*)d_ws;
    const float2* cW60 = (const float2*)(ws + OFF_W60);
    const float*  cW2J = ws + OFF_W2J;
    const float*  cDM1 = ws + OFF_DM1;
    const float2* cY1B = (const float2*)(ws + OFF_Y1B);
    const float*  gD1R = ws + OFF_D1R;
    const float*  gDM2 = ws + OFF_DM2;
    const float2* cY2B = (const float2*)(ws + OFF_Y2B);
    const float*  gD2R = ws + OFF_D2R;
    const float2* gT19 = (const float2*)(ws + OFF_T19U);
    const float2* gT11 = (const float2*)(ws + OFF_T11V);
    const float2* gT12 = (const float2*)(ws + OFF_T12U);
    const int*    gTABA = (const int*)(ws + OFF_TABA);
    const int*    gTABB = (const int*)(ws + OFF_TABB);
    const int*    gSORD = (const int*)(ws + OFF_SORD);

    float2* xh   = (float2*)(ws + OFF_END);          // 128*60*19
    float2* X    = xh + BT * 60 * 19;                // 100*128
    float2* Yk1  = X + 100 * BT;                     // 100*20
    float2* Yk2  = Yk1 + 100 * 20;                   // 40*286*20
    float2* X2   = Yk2 + 40 * 286 * 20;              // 128*286*20  [b][k2][i]
    float*  feat = (float*)(X2 + (size_t)BT * 5720); // 128*40
    float2* Z2   = (float2*)(feat + BT * 40);        // 128*40*286

    k_init<<<(N_INIT + NT - 1) / NT, NT, 0, stream>>>(ws);
    k_dft_alpha<<<(BT * 60 * 19 + NT - 1) / NT, NT, 0, stream>>>(x, cW60, xh);
    k_X1<<<(100 * BT + NT - 1) / NT, NT, 0, stream>>>(xh, cDM1, X);
    k_Yk1<<<(100 * 20 + NT - 1) / NT, NT, 0, stream>>>(k1, cY1B, Yk1);
    k_Yk2<<<286, NT, 0, stream>>>(k2, cY2B, Yk2);
    k_stage1<<<BT * 20, S1NT, 0, stream>>>(X, Yk1, gD1R, gDM2, gT19, gT11, gTABA, gTABB, gSORD, X2);
    k_Z2<<<320, NT, 0, stream>>>(X2, Yk2, gTABB, Z2);
    k_stage2b<<<BT * 40, S2NT, 0, stream>>>(Z2, gD2R, gT12, cW2J, feat);
    k_out<<<(BT * 10 + NT - 1) / NT, NT, 0, stream>>>(feat, wO, bO, out);
}

// Round 5
// 780.616 us; speedup vs baseline: 1.4639x; 1.4639x over previous
//
#include <hip/hip_runtime.h>
#include <cmath>

#define NT 256
#define BT 128

// ---------------- ws float-offsets for constant tables ----------------
#define OFF_W60   0          // 19*60 complex
#define OFF_E20   2280       // legacy
#define OFF_E12   2320       // legacy
#define OFF_W2J   2344       // 12 floats
#define OFF_DM1   2356       // 100*60
#define OFF_Y1B   8356       // 100*24 complex
#define OFF_D1R   13156      // [j=20][flat=1330] (2l+1)*d^l at beta1
#define OFF_DM2   39756      // [j=20][k2=286]  w1[j]*d^l(beta1_j)
#define OFF_Y2B   45476      // 286*192 complex
#define OFF_D2R   155300     // [j=12][flat=286] (2l+1)*d^l at beta2
#define OFF_T19U  158732     // 20x19 complex [c][n] e^{+2pi i n c/20}
#define OFF_T11V  159492     // 11x20 complex [r][c] e^{-2pi i (r-5) c/20}
#define OFF_T12U  159932     // 12x11 complex [c][n] e^{+2pi i n c/12}
#define OFF_TABA  160196     // 1330 int packed (l | mi<<8 | ni<<16)
#define OFF_TABB  161526     // 286 int packed
#define OFF_END   161812
#define N_INIT    102596

__constant__ int c_ZB1[10] = {0,1,10,35,84,165,286,455,680,969};
__constant__ int c_ZB2[6]  = {0,1,10,35,84,165};
__constant__ int c_BOFF[6] = {0,22,208,718,1712,3350};  // padded row offsets for k_Z2 LDS

// wave-local sync: per-wave-private LDS phase buffers only.
__device__ inline void wsync() {
    __asm__ volatile("" ::: "memory");
    __builtin_amdgcn_s_waitcnt(0xC07F);   // vmcnt=63, expcnt=7, lgkmcnt=0
    __builtin_amdgcn_wave_barrier();
    __asm__ volatile("" ::: "memory");
}

// ---------------- fp64 helpers for the init kernel ----------------
__device__ inline double dipow(double x, int e) {
    double r = 1.0;
    for (int i = 0; i < e; ++i) r *= x;
    return r;
}

__device__ double wigd(const double* F, int l, int mp, int m, double beta) {
    double cb = cos(beta * 0.5), sb = sin(beta * 0.5);
    int smin = m - mp; if (smin < 0) smin = 0;
    int smax = l + m;  if (l - mp < smax) smax = l - mp;
    double pref = sqrt(F[l+mp] * F[l-mp] * F[l+m] * F[l-m]);
    double sum = 0.0;
    for (int s = smin; s <= smax; ++s) {
        double t = pref / (F[l+m-s] * F[s] * F[mp-m+s] * F[l-mp-s]);
        t *= dipow(cb, 2*l + m - mp - 2*s) * dipow(sb, mp - m + 2*s);
        sum += ((mp - m + s) & 1) ? -t : t;
    }
    return sum;
}

__device__ double qwj(int bnd, int j) {
    const double PI = 3.14159265358979323846;
    double theta = PI * (2*j + 1) / (4.0 * bnd);
    double s = 0.0;
    for (int k = 0; k < bnd; ++k) s += sin(theta * (2*k + 1)) / (2*k + 1);
    return 2.0 / bnd * sin(theta) * s;
}

// ---------------- init ----------------
__global__ void k_init(float* __restrict__ ws) {
    int idx = blockIdx.x * blockDim.x + threadIdx.x;
    if (idx >= N_INIT) return;
    double F[20];
    F[0] = 1.0;
    #pragma unroll
    for (int i = 1; i < 20; ++i) F[i] = F[i-1] * i;
    const double PI = 3.14159265358979323846;

    if (idx < 1140) {                       // W60
        int r = idx / 60, a = idx % 60;
        double ang = -2.0 * PI * (double)((r - 9) * a) / 60.0;
        ws[OFF_W60 + 2*idx]     = (float)cos(ang);
        ws[OFF_W60 + 2*idx + 1] = (float)sin(ang);
    } else if (idx < 1160) {
        int t = idx - 1140;
        double ang = 2.0 * PI * t / 20.0;
        ws[OFF_E20 + 2*t]     = (float)cos(ang);
        ws[OFF_E20 + 2*t + 1] = (float)sin(ang);
    } else if (idx < 1172) {
        int t = idx - 1160;
        double ang = 2.0 * PI * t / 12.0;
        ws[OFF_E12 + 2*t]     = (float)cos(ang);
        ws[OFF_E12 + 2*t + 1] = (float)sin(ang);
    } else if (idx < 1184) {                // W2J
        int j = idx - 1172;
        ws[OFF_W2J + j] = (float)qwj(6, j);
    } else if (idx < 7184) {                // DM1[k][j]
        int e = idx - 1184; int k = e / 60, j = e % 60;
        int l = 0; while ((l + 1) * (l + 1) <= k) ++l;
        int m = k - l*l - l;
        double beta = PI * (2*j + 1) / 120.0;
        ws[OFF_DM1 + e] = (float)(qwj(30, j) * wigd(F, l, m, 0, beta));
    } else if (idx < 9584) {                // Y1B
        int e = idx - 7184; int k = e / 24, g = e % 24;
        int l = 0; while ((l + 1) * (l + 1) <= k) ++l;
        int m = k - l*l - l;
        int bi = g / 8, ai = g % 8;
        double beta  = (bi + 1) * (PI / 8.0) / 3.0;
        double alpha = 2.0 * PI * ai / 8.0;
        double d = wigd(F, l, m, 0, beta);
        double ph = -(double)m * alpha;
        ws[OFF_Y1B + 2*e]     = (float)(d * cos(ph));
        ws[OFF_Y1B + 2*e + 1] = (float)(d * sin(ph));
    } else if (idx < 36184) {               // D1R [j][flat], prescaled by (2l+1)
        int e = idx - 9584; int j = e / 1330, t = e % 1330;
        int l = 0; while (l < 9 && t >= c_ZB1[l+1]) ++l;
        int L = 2*l + 1, loc = t - c_ZB1[l];
        int mi = loc / L, ni = loc % L;
        double beta = PI * (2*j + 1) / 40.0;
        ws[OFF_D1R + e] = (float)((double)L * wigd(F, l, mi - l, ni - l, beta));
    } else if (idx < 41904) {               // DM2 [j][k2]
        int e = idx - 36184; int j = e / 286, k2 = e % 286;
        int l = 0; while (l < 5 && k2 >= c_ZB2[l+1]) ++l;
        int L = 2*l + 1, loc = k2 - c_ZB2[l];
        int mi = loc / L, ni = loc % L;
        double beta = PI * (2*j + 1) / 40.0;
        ws[OFF_DM2 + e] = (float)(qwj(10, j) * wigd(F, l, mi - l, ni - l, beta));
    } else if (idx < 96816) {               // Y2B
        int e = idx - 41904; int k2 = e / 192, g = e % 192;
        int l = 0; while (l < 5 && k2 >= c_ZB2[l+1]) ++l;
        int L = 2*l + 1, loc = k2 - c_ZB2[l];
        int m = loc / L - l, n = loc % L - l;
        int bi = g / 64, ai = (g / 8) % 8, ci = g % 8;
        double beta  = (bi + 1) * (PI / 8.0) / 3.0;
        double alpha = 2.0 * PI * ai / 8.0;
        double gamma = (-2.0 * PI + ci * (PI / 2.0)) - alpha;
        double d = wigd(F, l, m, n, beta);
        double ph = -((double)m * alpha + (double)n * gamma);
        ws[OFF_Y2B + 2*e]     = (float)(d * cos(ph));
        ws[OFF_Y2B + 2*e + 1] = (float)(d * sin(ph));
    } else if (idx < 100248) {              // D2R [j][flat], prescaled by (2l+1)
        int e = idx - 96816; int j = e / 286, t = e % 286;
        int l = 0; while (l < 5 && t >= c_ZB2[l+1]) ++l;
        int L = 2*l + 1, loc = t - c_ZB2[l];
        int mi = loc / L, ni = loc % L;
        double beta = PI * (2*j + 1) / 24.0;
        ws[OFF_D2R + e] = (float)((double)L * wigd(F, l, mi - l, ni - l, beta));
    } else if (idx < 100628) {              // T19U [c][n]
        int e = idx - 100248; int c = e / 19, n = e % 19 - 9;
        double ang = 2.0 * PI * (double)(n * c) / 20.0;
        ws[OFF_T19U + 2*e]     = (float)cos(ang);
        ws[OFF_T19U + 2*e + 1] = (float)sin(ang);
    } else if (idx < 100848) {              // T11V [r][c]
        int e = idx - 100628; int r = e / 20, c = e % 20;
        double ang = -2.0 * PI * (double)((r - 5) * c) / 20.0;
        ws[OFF_T11V + 2*e]     = (float)cos(ang);
        ws[OFF_T11V + 2*e + 1] = (float)sin(ang);
    } else if (idx < 100980) {              // T12U [c][n]
        int e = idx - 100848; int c = e / 11, n = e % 11 - 5;
        double ang = 2.0 * PI * (double)(n * c) / 12.0;
        ws[OFF_T12U + 2*e]     = (float)cos(ang);
        ws[OFF_T12U + 2*e + 1] = (float)sin(ang);
    } else if (idx < 102310) {              // TABA
        int t = idx - 100980;
        int l = 0; while (l < 9 && t >= c_ZB1[l+1]) ++l;
        int L = 2*l + 1, loc = t - c_ZB1[l];
        ((int*)ws)[OFF_TABA + t] = l | ((loc / L) << 8) | ((loc % L) << 16);
    } else {                                // TABB
        int t = idx - 102310;
        int l = 0; while (l < 5 && t >= c_ZB2[l+1]) ++l;
        int L = 2*l + 1, loc = t - c_ZB2[l];
        ((int*)ws)[OFF_TABB + t] = l | ((loc / L) << 8) | ((loc % L) << 16);
    }
}

// ---------------- small pipeline kernels ----------------
__global__ void k_dft_alpha(const float* __restrict__ x, const float2* __restrict__ W60,
                            float2* __restrict__ xh) {
    int idx = blockIdx.x * blockDim.x + threadIdx.x;
    if (idx >= BT * 60 * 19) return;
    int r = idx % 19;
    int j = (idx / 19) % 60;
    int b = idx / (19 * 60);
    const float* xr = x + (b * 60 + j) * 60;
    const float2* wr = W60 + r * 60;
    float re = 0.f, im = 0.f;
    for (int a = 0; a < 60; ++a) {
        float v = xr[a];
        float2 w = wr[a];
        re += v * w.x; im += v * w.y;
    }
    xh[idx] = make_float2(re * (1.f / 60.f), im * (1.f / 60.f));
}

__global__ void k_X1(const float2* __restrict__ xh, const float* __restrict__ DM1,
                     float2* __restrict__ X) {
    int idx = blockIdx.x * blockDim.x + threadIdx.x;
    if (idx >= 100 * BT) return;
    int b = idx % BT, k = idx / BT;
    int l = 0; while ((l + 1) * (l + 1) <= k) ++l;
    int r = (k - l*l - l) + 9;
    float re = 0.f, im = 0.f;
    for (int j = 0; j < 60; ++j) {
        float d = DM1[k * 60 + j];
        float2 v = xh[(b * 60 + j) * 19 + r];
        re += d * v.x; im += d * v.y;
    }
    X[k * BT + b] = make_float2(re, im);
}

__global__ void k_Yk1(const float* __restrict__ k1, const float2* __restrict__ Y1B,
                      float2* __restrict__ Yk1) {
    int idx = blockIdx.x * blockDim.x + threadIdx.x;
    if (idx >= 100 * 20) return;
    int o = idx % 20, k = idx / 20;
    float re = 0.f, im = 0.f;
    for (int g = 0; g < 24; ++g) {
        float2 y = Y1B[k * 24 + g];
        float w = k1[o * 24 + g];
        re += y.x * w; im += y.y * w;
    }
    const float SC1 = 0.20412414523193154f;  // 1/sqrt(24)
    Yk1[idx] = make_float2(re * SC1, im * SC1);
}

// Yk2 layout: [o][k2][i]; one block per k2, Y2B row staged in LDS
__global__ __launch_bounds__(NT) void k_Yk2(const float* __restrict__ k2in,
                                            const float2* __restrict__ Y2B,
                                            float2* __restrict__ Yk2) {
    const int k = blockIdx.x;      // 0..285
    const int tid = threadIdx.x;
    __shared__ __align__(16) float2 sY[192];
    for (int t = tid; t < 192; t += NT) sY[t] = Y2B[k * 192 + t];
    __syncthreads();
    const float4* sY4 = (const float4*)sY;
    const float SC2 = 0.016137430609197573f; // 1/sqrt(192*20)
    for (int t = tid; t < 800; t += NT) {
        int o = t / 20, i = t % 20;
        const float4* kp = (const float4*)(k2in + (i * 40 + o) * 192);
        float re = 0.f, im = 0.f;
        #pragma unroll 4
        for (int p = 0; p < 48; ++p) {
            float4 w = kp[p];
            float4 y01 = sY4[2*p], y23 = sY4[2*p + 1];
            re += w.x * y01.x + w.y * y01.z + w.z * y23.x + w.w * y23.z;
            im += w.x * y01.y + w.y * y01.w + w.z * y23.y + w.w * y23.w;
        }
        Yk2[(o * 286 + k) * 20 + i] = make_float2(re * SC2, im * SC2);
    }
}

// ---------------- stage 1: one block per (b,f1); wave-owned j; 2x2 register-blocked DFTs ----------------
// X2 layout: [b][k2][f1]
__global__ __launch_bounds__(NT) void k_stage1(
    const float2* __restrict__ X, const float2* __restrict__ Yk1,
    const float* __restrict__ gD1R, const float* __restrict__ gDM2,
    const float2* __restrict__ gT19, const float2* __restrict__ gT11,
    const int* __restrict__ gTABA, const int* __restrict__ gTABB,
    float2* __restrict__ X2g) {
    const int b = blockIdx.x % BT;
    const int f = blockIdx.x / BT;   // 0..19
    const int tid = threadIdx.x;
    const int wv = tid >> 6, lane = tid & 63;

    __shared__ __align__(16) float2 sZ[1330];
    __shared__ __align__(16) float2 sX2w[4][286];
    __shared__ __align__(16) float2 sT19[440];   // [c][n], stride 22
    __shared__ __align__(16) float2 sT11[220];   // [r][c], stride 20
    __shared__ __align__(16) float2 sA[4][424];  // per-wave: S(19x22) | x1(400f) | G(121)
    __shared__ __align__(16) float2 sB[4][440];  // per-wave: U(20x22) | V(11x22)

    for (int t = tid; t < 380; t += NT) sT19[(t / 19) * 22 + (t % 19)] = gT19[t];
    for (int t = tid; t < 220; t += NT) sT11[t] = gT11[t];
    for (int t = tid; t < 286; t += NT) {
        sX2w[0][t] = make_float2(0.f, 0.f); sX2w[1][t] = make_float2(0.f, 0.f);
        sX2w[2][t] = make_float2(0.f, 0.f); sX2w[3][t] = make_float2(0.f, 0.f);
    }
    for (int t = tid; t < 1330; t += NT) {
        int p = gTABA[t];
        int l = p & 255, mi = (p >> 8) & 255, ni = p >> 16;
        float2 a = X[(l*l + mi) * BT + b];
        float2 y = Yk1[(l*l + ni) * 20 + f];
        sZ[t] = make_float2(a.x * y.x + a.y * y.y, a.y * y.x - a.x * y.y);
    }
    __syncthreads();

    float2* S   = sA[wv];            // [mi][ni] stride 22
    float2* U   = sB[wv];            // [c][mi] stride 22
    float*  x1  = (float*)sA[wv];    // [a][c] stride 20 (floats)
    float2* V   = sB[wv];            // [n][a] stride 22
    float2* G   = sA[wv];            // [m'][n'] stride 11
    float2* myX2 = sX2w[wv];

    for (int jj = 0; jj < 5; ++jj) {
        const int j = wv + 4 * jj;

        // ---- S[m][n] = sum_l (2l+1)d^l_j[m,n] Z[l,m,n]  (D1R prescaled)
        {
            const float* dp = gD1R + j * 1330;
            for (int t = lane; t < 361; t += 64) {
                int mi = t / 19, ni = t % 19;
                int m = mi - 9, n = ni - 9;
                int am = m < 0 ? -m : m, an = n < 0 ? -n : n;
                int lmin = am > an ? am : an;
                float re = 0.f, im = 0.f;
                for (int l = lmin; l < 10; ++l) {
                    int L = 2*l + 1;
                    int o = c_ZB1[l] + (m + l) * L + (n + l);
                    float dv = dp[o];
                    float2 z = sZ[o];
                    re += dv * z.x; im += dv * z.y;
                }
                S[mi * 22 + ni] = make_float2(re, im);
            }
        }
        wsync();

        // ---- U[m][c] = sum_n S[m][n] T19[c][n]; 2x2 blocks (mi0,mi1)x(c0,c1); write U[c][m]
        for (int t = lane; t < 100; t += 64) {
            int mp = t / 10, cp = t % 10;
            int mi0 = 2 * mp, mi1 = mi0 + 1;
            bool has1 = (mi1 < 19);
            const float4* s0 = (const float4*)(S + mi0 * 22);
            const float4* s1 = (const float4*)(S + (has1 ? mi1 : mi0) * 22);
            const float4* w0p = (const float4*)(sT19 + cp * 22);
            const float4* w1p = (const float4*)(sT19 + (cp + 10) * 22);
            float r00=0.f,i00=0.f,r01=0.f,i01=0.f,r10=0.f,i10=0.f,r11=0.f,i11=0.f;
            #pragma unroll
            for (int p = 0; p < 9; ++p) {
                float4 a0 = s0[p], a1 = s1[p], w0 = w0p[p], w1 = w1p[p];
                r00 += a0.x*w0.x - a0.y*w0.y + a0.z*w0.z - a0.w*w0.w;
                i00 += a0.x*w0.y + a0.y*w0.x + a0.z*w0.w + a0.w*w0.z;
                r01 += a0.x*w1.x - a0.y*w1.y + a0.z*w1.z - a0.w*w1.w;
                i01 += a0.x*w1.y + a0.y*w1.x + a0.z*w1.w + a0.w*w1.z;
                r10 += a1.x*w0.x - a1.y*w0.y + a1.z*w0.z - a1.w*w0.w;
                i10 += a1.x*w0.y + a1.y*w0.x + a1.z*w0.w + a1.w*w0.z;
                r11 += a1.x*w1.x - a1.y*w1.y + a1.z*w1.z - a1.w*w1.w;
                i11 += a1.x*w1.y + a1.y*w1.x + a1.z*w1.w + a1.w*w1.z;
            }
            {
                float2 a0 = S[mi0*22 + 18], a1 = S[(has1 ? mi1 : mi0)*22 + 18];
                float2 w0 = sT19[cp*22 + 18], w1 = sT19[(cp+10)*22 + 18];
                r00 += a0.x*w0.x - a0.y*w0.y; i00 += a0.x*w0.y + a0.y*w0.x;
                r01 += a0.x*w1.x - a0.y*w1.y; i01 += a0.x*w1.y + a0.y*w1.x;
                r10 += a1.x*w0.x - a1.y*w0.y; i10 += a1.x*w0.y + a1.y*w0.x;
                r11 += a1.x*w1.x - a1.y*w1.y; i11 += a1.x*w1.y + a1.y*w1.x;
            }
            U[cp*22 + mi0]      = make_float2(r00, i00);
            U[(cp+10)*22 + mi0] = make_float2(r01, i01);
            if (has1) {
                U[cp*22 + mi1]      = make_float2(r10, i10);
                U[(cp+10)*22 + mi1] = make_float2(r11, i11);
            }
        }
        wsync();

        // ---- x1[a][c] = relu(Re sum_m U[m][c] T19[a][m]); 2x2 blocks (a0,a1)x(c0,c1)
        for (int t = lane; t < 100; t += 64) {
            int ap = t / 10, cp = t % 10;
            int a0 = ap, a1 = ap + 10, c0 = cp, c1 = cp + 10;
            const float4* u0 = (const float4*)(U + c0 * 22);
            const float4* u1 = (const float4*)(U + c1 * 22);
            const float4* w0p = (const float4*)(sT19 + a0 * 22);
            const float4* w1p = (const float4*)(sT19 + a1 * 22);
            float s00=0.f,s01=0.f,s10=0.f,s11=0.f;
            #pragma unroll
            for (int p = 0; p < 9; ++p) {
                float4 ua = u0[p], ub = u1[p], w0 = w0p[p], w1 = w1p[p];
                s00 += ua.x*w0.x - ua.y*w0.y + ua.z*w0.z - ua.w*w0.w;
                s10 += ua.x*w1.x - ua.y*w1.y + ua.z*w1.z - ua.w*w1.w;
                s01 += ub.x*w0.x - ub.y*w0.y + ub.z*w0.z - ub.w*w0.w;
                s11 += ub.x*w1.x - ub.y*w1.y + ub.z*w1.z - ub.w*w1.w;
            }
            {
                float2 ua = U[c0*22 + 18], ub = U[c1*22 + 18];
                float2 w0 = sT19[a0*22 + 18], w1 = sT19[a1*22 + 18];
                s00 += ua.x*w0.x - ua.y*w0.y;
                s10 += ua.x*w1.x - ua.y*w1.y;
                s01 += ub.x*w0.x - ub.y*w0.y;
                s11 += ub.x*w1.x - ub.y*w1.y;
            }
            x1[a0*20 + c0] = s00 > 0.f ? s00 : 0.f;
            x1[a0*20 + c1] = s01 > 0.f ? s01 : 0.f;
            x1[a1*20 + c0] = s10 > 0.f ? s10 : 0.f;
            x1[a1*20 + c1] = s11 > 0.f ? s11 : 0.f;
        }
        wsync();

        // ---- V[a][n] = sum_c x1[a][c] T11[n][c]; pairs (a0,a1) share T-row; write V[n][a]
        for (int t = lane; t < 110; t += 64) {
            int n = t / 10, ap = t % 10;
            int a0 = ap, a1 = ap + 10;
            const float4* xa = (const float4*)(x1 + a0 * 20);
            const float4* xb = (const float4*)(x1 + a1 * 20);
            const float4* tp = (const float4*)(sT11 + n * 20);
            float r0=0.f,i0=0.f,r1=0.f,i1=0.f;
            #pragma unroll
            for (int p = 0; p < 5; ++p) {
                float4 va = xa[p], vb = xb[p];
                float4 t01 = tp[2*p], t23 = tp[2*p + 1];
                r0 += va.x*t01.x + va.y*t01.z + va.z*t23.x + va.w*t23.z;
                i0 += va.x*t01.y + va.y*t01.w + va.z*t23.y + va.w*t23.w;
                r1 += vb.x*t01.x + vb.y*t01.z + vb.z*t23.x + vb.w*t23.z;
                i1 += vb.x*t01.y + vb.y*t01.w + vb.z*t23.y + vb.w*t23.w;
            }
            V[n*22 + a0] = make_float2(r0, i0);
            V[n*22 + a1] = make_float2(r1, i1);
        }
        wsync();

        // ---- G[m][n] = sum_a V[n][a] T11[m][a]; pairs (m0,m1) share V-row
        for (int t = lane; t < 66; t += 64) {
            int mp = t / 11, ni = t % 11;
            int m0 = 2 * mp, m1 = m0 + 1;
            bool has1 = (m1 < 11);
            const float4* vp = (const float4*)(V + ni * 22);
            const float4* t0 = (const float4*)(sT11 + m0 * 20);
            const float4* t1 = (const float4*)(sT11 + (has1 ? m1 : m0) * 20);
            float r0=0.f,i0=0.f,r1=0.f,i1=0.f;
            #pragma unroll
            for (int q = 0; q < 10; ++q) {
                float4 v = vp[q], w0 = t0[q], w1 = t1[q];
                r0 += v.x*w0.x - v.y*w0.y + v.z*w0.z - v.w*w0.w;
                i0 += v.x*w0.y + v.y*w0.x + v.z*w0.w + v.w*w0.z;
                r1 += v.x*w1.x - v.y*w1.y + v.z*w1.z - v.w*w1.w;
                i1 += v.x*w1.y + v.y*w1.x + v.z*w1.w + v.w*w1.z;
            }
            G[m0*11 + ni] = make_float2(r0, i0);
            if (has1) G[m1*11 + ni] = make_float2(r1, i1);
        }
        wsync();

        // ---- X2w[k2] += DM2[j][k2] * G[...]
        {
            const float* dmp = gDM2 + j * 286;
            for (int k2 = lane; k2 < 286; k2 += 64) {
                int p = gTABB[k2];
                int l = p & 255, mi = (p >> 8) & 255, ni = p >> 16;
                float dm = dmp[k2];
                float2 g = G[(mi - l + 5) * 11 + (ni - l + 5)];
                myX2[k2].x += dm * g.x;
                myX2[k2].y += dm * g.y;
            }
        }
        wsync();
    }
    __syncthreads();

    for (int t = tid; t < 286; t += NT) {
        float2 v0 = sX2w[0][t], v1 = sX2w[1][t], v2 = sX2w[2][t], v3 = sX2w[3][t];
        X2g[b * 5720 + t * 20 + f] =
            make_float2((v0.x + v1.x + v2.x + v3.x) * (1.f / 400.f),
                        (v0.y + v1.y + v2.y + v3.y) * (1.f / 400.f));
    }
}

// ---------------- stage 2a: Z[b][o][k2] = sum_{k,i} A . conj(B) ----------------
__global__ __launch_bounds__(NT) void k_Z2(
    const float2* __restrict__ X2g, const float2* __restrict__ Yk2,
    const int* __restrict__ gTABB, float2* __restrict__ Z2g) {
    const int bt = blockIdx.x & 7;        // 0..7
    const int o  = blockIdx.x >> 3;       // 0..39
    const int b0 = bt * 16;
    const int tid = threadIdx.x;

    __shared__ __align__(16) float2 sB[5792];

    const float2* Bg = Yk2 + o * 5720;
    for (int e = tid; e < 5720; e += NT) {
        int k2 = e / 20, i = e % 20;
        int p = gTABB[k2];
        int l = p & 255, r = (p >> 8) & 255, kk = p >> 16;
        sB[c_BOFF[l] + r * (40 * l + 22) + kk * 20 + i] = Bg[e];
    }
    __syncthreads();

    for (int q = tid; q < 16 * 286; q += NT) {
        int b_local = q / 286, t = q % 286;
        int p = gTABB[t];
        int l = p & 255, mi = (p >> 8) & 255, ni = p >> 16;
        int L = 2 * l + 1;
        const float4* ap = (const float4*)(X2g + (size_t)(b0 + b_local) * 5720
                                           + (c_ZB2[l] + mi * L) * 20);
        const float4* bp = (const float4*)(sB + c_BOFF[l] + ni * (40 * l + 22));
        float re = 0.f, im = 0.f;
        int n4 = 10 * L;
        for (int p4 = 0; p4 < n4; ++p4) {
            float4 a = ap[p4], y = bp[p4];
            re += a.x * y.x + a.y * y.y + a.z * y.z + a.w * y.w;
            im += a.y * y.x - a.x * y.y + a.w * y.z - a.z * y.w;
        }
        Z2g[((size_t)(b0 + b_local) * 40 + o) * 286 + t] = make_float2(re, im);
    }
}

// ---------------- stage 2b: per (b,o): j-loop + integrate ----------------
__global__ __launch_bounds__(NT) void k_stage2b(
    const float2* __restrict__ Z2g, const float* __restrict__ gD2R,
    const float2* __restrict__ gT12, const float* __restrict__ gW2J,
    float* __restrict__ feat) {
    const int b = blockIdx.x % BT;
    const int o = blockIdx.x / BT;   // 0..39
    const int tid = threadIdx.x;
    const int wv = tid >> 6, lane = tid & 63;

    __shared__ __align__(16) float2 sZb[286];
    __shared__ __align__(16) float2 sT12[168];   // [c][n], stride 14
    __shared__ __align__(16) float2 sS[4][154];  // [mi][ni], stride 14
    __shared__ __align__(16) float2 sU[4][168];  // [c][mi], stride 14
    __shared__ float sredw[4];

    const float2* Zr = Z2g + ((size_t)b * 40 + o) * 286;
    for (int t = tid; t < 286; t += NT) sZb[t] = Zr[t];
    for (int t = tid; t < 132; t += NT) sT12[(t / 11) * 14 + (t % 11)] = gT12[t];
    __syncthreads();

    float2* S = sS[wv];
    float2* U = sU[wv];
    float facc = 0.f;

    for (int jj = 0; jj < 3; ++jj) {
        const int j = wv + 4 * jj;

        {
            const float* dp = gD2R + j * 286;
            for (int t = lane; t < 121; t += 64) {
                int mi = t / 11, ni = t % 11;
                int m = mi - 5, n = ni - 5;
                int am = m < 0 ? -m : m, an = n < 0 ? -n : n;
                int lmin = am > an ? am : an;
                float re = 0.f, im = 0.f;
                for (int l = lmin; l < 6; ++l) {
                    int L = 2*l + 1;
                    int off = c_ZB2[l] + (m + l) * L + (n + l);
                    float dv = dp[off];
                    float2 z = sZb[off];
                    re += dv * z.x; im += dv * z.y;
                }
                S[mi * 14 + ni] = make_float2(re, im);
            }
        }
        wsync();

        for (int t = lane; t < 132; t += 64) {
            int mi = t / 12, c = t % 12;
            const float4* sp = (const float4*)(S + mi * 14);
            const float4* tp = (const float4*)(sT12 + c * 14);
            float re = 0.f, im = 0.f;
            #pragma unroll
            for (int p = 0; p < 5; ++p) {
                float4 s = sp[p], w = tp[p];
                re += s.x * w.x - s.y * w.y + s.z * w.z - s.w * w.w;
                im += s.x * w.y + s.y * w.x + s.z * w.w + s.w * w.z;
            }
            float2 s1 = S[mi * 14 + 10], w1 = sT12[c * 14 + 10];
            re += s1.x * w1.x - s1.y * w1.y;
            im += s1.x * w1.y + s1.y * w1.x;
            U[c * 14 + mi] = make_float2(re, im);
        }
        wsync();

        {
            float wj = gW2J[j];
            for (int t = lane; t < 144; t += 64) {
                int a = t / 12, c = t % 12;
                const float4* up = (const float4*)(U + c * 14);
                const float4* tp = (const float4*)(sT12 + a * 14);
                float acc = 0.f;
                #pragma unroll
                for (int p = 0; p < 5; ++p) {
                    float4 u = up[p], w = tp[p];
                    acc += u.x * w.x - u.y * w.y + u.z * w.z - u.w * w.w;
                }
                float2 u1 = U[c * 14 + 10], w1 = sT12[a * 14 + 10];
                acc += u1.x * w1.x - u1.y * w1.y;
                if (acc > 0.f) facc += wj * acc;
            }
        }
        wsync();
    }

    #pragma unroll
    for (int d = 32; d > 0; d >>= 1) facc += __shfl_down(facc, d, 64);
    if (lane == 0) sredw[wv] = facc;
    __syncthreads();
    if (tid == 0) {
        const float INTEG = 0.27415567780803774f;  // (2*pi/12)^2
        feat[b * 40 + o] = (sredw[0] + sredw[1] + sredw[2] + sredw[3]) * INTEG;
    }
}

__global__ void k_out(const float* __restrict__ feat, const float* __restrict__ w,
                      const float* __restrict__ bias, float* __restrict__ out) {
    int idx = blockIdx.x * blockDim.x + threadIdx.x;
    if (idx >= BT * 10) return;
    int fo = idx % 10, b = idx / 10;
    float acc = bias[fo];
    for (int o2 = 0; o2 < 40; ++o2) acc += feat[b * 40 + o2] * w[fo * 40 + o2];
    out[idx] = acc;
}

extern "C" void kernel_launch(void* const* d_in, const int* in_sizes, int n_in,
                              void* d_out, int out_size, void* d_ws, size_t ws_size,
                              hipStream_t stream) {
    (void)in_sizes; (void)n_in; (void)out_size; (void)ws_size;
    const float* x   = (const float*)d_in[0];
    const float* k1  = (const float*)d_in[1];
    const float* k2  = (const float*)d_in[2];
    const float* wO  = (const float*)d_in[3];
    const float* bO  = (const float*)d_in[4];
    float* out = (float*)d_out;

    float* ws = (float*)d_ws;
    const float2* cW60 = (const float2*)(ws + OFF_W60);
    const float*  cW2J = ws + OFF_W2J;
    const float*  cDM1 = ws + OFF_DM1;
    const float2* cY1B = (const float2*)(ws + OFF_Y1B);
    const float*  gD1R = ws + OFF_D1R;
    const float*  gDM2 = ws + OFF_DM2;
    const float2* cY2B = (const float2*)(ws + OFF_Y2B);
    const float*  gD2R = ws + OFF_D2R;
    const float2* gT19 = (const float2*)(ws + OFF_T19U);
    const float2* gT11 = (const float2*)(ws + OFF_T11V);
    const float2* gT12 = (const float2*)(ws + OFF_T12U);
    const int*    gTABA = (const int*)(ws + OFF_TABA);
    const int*    gTABB = (const int*)(ws + OFF_TABB);

    float2* xh   = (float2*)(ws + OFF_END);          // 128*60*19
    float2* X    = xh + BT * 60 * 19;                // 100*128
    float2* Yk1  = X + 100 * BT;                     // 100*20
    float2* Yk2  = Yk1 + 100 * 20;                   // 40*286*20
    float2* X2   = Yk2 + 40 * 286 * 20;              // 128*286*20  [b][k2][i]
    float*  feat = (float*)(X2 + (size_t)BT * 5720); // 128*40
    float2* Z2   = (float2*)(feat + BT * 40);        // 128*40*286

    k_init<<<(N_INIT + NT - 1) / NT, NT, 0, stream>>>(ws);
    k_dft_alpha<<<(BT * 60 * 19 + NT - 1) / NT, NT, 0, stream>>>(x, cW60, xh);
    k_X1<<<(100 * BT + NT - 1) / NT, NT, 0, stream>>>(xh, cDM1, X);
    k_Yk1<<<(100 * 20 + NT - 1) / NT, NT, 0, stream>>>(k1, cY1B, Yk1);
    k_Yk2<<<286, NT, 0, stream>>>(k2, cY2B, Yk2);
    k_stage1<<<BT * 20, NT, 0, stream>>>(X, Yk1, gD1R, gDM2, gT19, gT11, gTABA, gTABB, X2);
    k_Z2<<<320, NT, 0, stream>>>(X2, Yk2, gTABB, Z2);
    k_stage2b<<<BT * 40, NT, 0, stream>>>(Z2, gD2R, gT12, cW2J, feat);
    k_out<<<(BT * 10 + NT - 1) / NT, NT, 0, stream>>>(feat, wO, bO, out);
}

// Round 6
// 545.527 us; speedup vs baseline: 2.0948x; 1.4309x over previous
//
#include <hip/hip_runtime.h>
#include <cmath>

#define NT 256
#define BT 128

// ---------------- ws float-offsets for constant tables ----------------
#define OFF_W60   0          // 19*60 complex
#define OFF_E20   2280       // legacy
#define OFF_E12   2320       // legacy
#define OFF_W2J   2344       // 12 floats
#define OFF_DM1   2356       // 100*60
#define OFF_Y1B   8356       // 100*24 complex
#define OFF_D1R   13156      // [j=20][flat=1330] (2l+1)*d^l at beta1
#define OFF_DM2   39756      // [j=20][k2=286]  w1[j]*d^l(beta1_j)
#define OFF_Y2B   45476      // 286*192 complex
#define OFF_D2R   155300     // [j=12][flat=286] (2l+1)*d^l at beta2
#define OFF_T19U  158732     // 20x19 complex [c][n] e^{+2pi i n c/20}
#define OFF_T11V  159492     // 11x20 complex [r][c] e^{-2pi i (r-5) c/20}
#define OFF_T12U  159932     // 12x11 complex [c][n] e^{+2pi i n c/12}
#define OFF_TABA  160196     // 1330 int packed (l | mi<<8 | ni<<16)
#define OFF_TABB  161526     // 286 int packed
#define OFF_TH19  161812     // 20x10 complex [a][mm] f*e^{+2pi i mm a/20}, f=1 (mm=0) else 2
#define OFF_TH12  162212     // 12x6 complex [a][mm] f*e^{+2pi i mm a/12}
#define OFF_TABH  162356     // 146 int packed (l | loc<<8): half items per l
#define OFF_END   162504
#define N_INIT    103014

__constant__ int c_ZB1[10] = {0,1,10,35,84,165,286,455,680,969};
__constant__ int c_ZB2[6]  = {0,1,10,35,84,165};
__constant__ int c_BOFF[6] = {0,22,208,718,1712,3350};  // padded row offsets for k_Z2 LDS

// wave-local sync: per-wave-private LDS phase buffers only.
__device__ inline void wsync() {
    __asm__ volatile("" ::: "memory");
    __builtin_amdgcn_s_waitcnt(0xC07F);   // vmcnt=63, expcnt=7, lgkmcnt=0
    __builtin_amdgcn_wave_barrier();
    __asm__ volatile("" ::: "memory");
}

// ---------------- fp64 helpers for the init kernel ----------------
__device__ inline double dipow(double x, int e) {
    double r = 1.0;
    for (int i = 0; i < e; ++i) r *= x;
    return r;
}

__device__ double wigd(const double* F, int l, int mp, int m, double beta) {
    double cb = cos(beta * 0.5), sb = sin(beta * 0.5);
    int smin = m - mp; if (smin < 0) smin = 0;
    int smax = l + m;  if (l - mp < smax) smax = l - mp;
    double pref = sqrt(F[l+mp] * F[l-mp] * F[l+m] * F[l-m]);
    double sum = 0.0;
    for (int s = smin; s <= smax; ++s) {
        double t = pref / (F[l+m-s] * F[s] * F[mp-m+s] * F[l-mp-s]);
        t *= dipow(cb, 2*l + m - mp - 2*s) * dipow(sb, mp - m + 2*s);
        sum += ((mp - m + s) & 1) ? -t : t;
    }
    return sum;
}

__device__ double qwj(int bnd, int j) {
    const double PI = 3.14159265358979323846;
    double theta = PI * (2*j + 1) / (4.0 * bnd);
    double s = 0.0;
    for (int k = 0; k < bnd; ++k) s += sin(theta * (2*k + 1)) / (2*k + 1);
    return 2.0 / bnd * sin(theta) * s;
}

// ---------------- init ----------------
__global__ void k_init(float* __restrict__ ws) {
    int idx = blockIdx.x * blockDim.x + threadIdx.x;
    if (idx >= N_INIT) return;
    double F[20];
    F[0] = 1.0;
    #pragma unroll
    for (int i = 1; i < 20; ++i) F[i] = F[i-1] * i;
    const double PI = 3.14159265358979323846;

    if (idx < 1140) {                       // W60
        int r = idx / 60, a = idx % 60;
        double ang = -2.0 * PI * (double)((r - 9) * a) / 60.0;
        ws[OFF_W60 + 2*idx]     = (float)cos(ang);
        ws[OFF_W60 + 2*idx + 1] = (float)sin(ang);
    } else if (idx < 1160) {
        int t = idx - 1140;
        double ang = 2.0 * PI * t / 20.0;
        ws[OFF_E20 + 2*t]     = (float)cos(ang);
        ws[OFF_E20 + 2*t + 1] = (float)sin(ang);
    } else if (idx < 1172) {
        int t = idx - 1160;
        double ang = 2.0 * PI * t / 12.0;
        ws[OFF_E12 + 2*t]     = (float)cos(ang);
        ws[OFF_E12 + 2*t + 1] = (float)sin(ang);
    } else if (idx < 1184) {                // W2J
        int j = idx - 1172;
        ws[OFF_W2J + j] = (float)qwj(6, j);
    } else if (idx < 7184) {                // DM1[k][j]
        int e = idx - 1184; int k = e / 60, j = e % 60;
        int l = 0; while ((l + 1) * (l + 1) <= k) ++l;
        int m = k - l*l - l;
        double beta = PI * (2*j + 1) / 120.0;
        ws[OFF_DM1 + e] = (float)(qwj(30, j) * wigd(F, l, m, 0, beta));
    } else if (idx < 9584) {                // Y1B
        int e = idx - 7184; int k = e / 24, g = e % 24;
        int l = 0; while ((l + 1) * (l + 1) <= k) ++l;
        int m = k - l*l - l;
        int bi = g / 8, ai = g % 8;
        double beta  = (bi + 1) * (PI / 8.0) / 3.0;
        double alpha = 2.0 * PI * ai / 8.0;
        double d = wigd(F, l, m, 0, beta);
        double ph = -(double)m * alpha;
        ws[OFF_Y1B + 2*e]     = (float)(d * cos(ph));
        ws[OFF_Y1B + 2*e + 1] = (float)(d * sin(ph));
    } else if (idx < 36184) {               // D1R [j][flat], prescaled by (2l+1)
        int e = idx - 9584; int j = e / 1330, t = e % 1330;
        int l = 0; while (l < 9 && t >= c_ZB1[l+1]) ++l;
        int L = 2*l + 1, loc = t - c_ZB1[l];
        int mi = loc / L, ni = loc % L;
        double beta = PI * (2*j + 1) / 40.0;
        ws[OFF_D1R + e] = (float)((double)L * wigd(F, l, mi - l, ni - l, beta));
    } else if (idx < 41904) {               // DM2 [j][k2]
        int e = idx - 36184; int j = e / 286, k2 = e % 286;
        int l = 0; while (l < 5 && k2 >= c_ZB2[l+1]) ++l;
        int L = 2*l + 1, loc = k2 - c_ZB2[l];
        int mi = loc / L, ni = loc % L;
        double beta = PI * (2*j + 1) / 40.0;
        ws[OFF_DM2 + e] = (float)(qwj(10, j) * wigd(F, l, mi - l, ni - l, beta));
    } else if (idx < 96816) {               // Y2B
        int e = idx - 41904; int k2 = e / 192, g = e % 192;
        int l = 0; while (l < 5 && k2 >= c_ZB2[l+1]) ++l;
        int L = 2*l + 1, loc = k2 - c_ZB2[l];
        int m = loc / L - l, n = loc % L - l;
        int bi = g / 64, ai = (g / 8) % 8, ci = g % 8;
        double beta  = (bi + 1) * (PI / 8.0) / 3.0;
        double alpha = 2.0 * PI * ai / 8.0;
        double gamma = (-2.0 * PI + ci * (PI / 2.0)) - alpha;
        double d = wigd(F, l, m, n, beta);
        double ph = -((double)m * alpha + (double)n * gamma);
        ws[OFF_Y2B + 2*e]     = (float)(d * cos(ph));
        ws[OFF_Y2B + 2*e + 1] = (float)(d * sin(ph));
    } else if (idx < 100248) {              // D2R [j][flat], prescaled by (2l+1)
        int e = idx - 96816; int j = e / 286, t = e % 286;
        int l = 0; while (l < 5 && t >= c_ZB2[l+1]) ++l;
        int L = 2*l + 1, loc = t - c_ZB2[l];
        int mi = loc / L, ni = loc % L;
        double beta = PI * (2*j + 1) / 24.0;
        ws[OFF_D2R + e] = (float)((double)L * wigd(F, l, mi - l, ni - l, beta));
    } else if (idx < 100628) {              // T19U [c][n]
        int e = idx - 100248; int c = e / 19, n = e % 19 - 9;
        double ang = 2.0 * PI * (double)(n * c) / 20.0;
        ws[OFF_T19U + 2*e]     = (float)cos(ang);
        ws[OFF_T19U + 2*e + 1] = (float)sin(ang);
    } else if (idx < 100848) {              // T11V [r][c]
        int e = idx - 100628; int r = e / 20, c = e % 20;
        double ang = -2.0 * PI * (double)((r - 5) * c) / 20.0;
        ws[OFF_T11V + 2*e]     = (float)cos(ang);
        ws[OFF_T11V + 2*e + 1] = (float)sin(ang);
    } else if (idx < 100980) {              // T12U [c][n]
        int e = idx - 100848; int c = e / 11, n = e % 11 - 5;
        double ang = 2.0 * PI * (double)(n * c) / 12.0;
        ws[OFF_T12U + 2*e]     = (float)cos(ang);
        ws[OFF_T12U + 2*e + 1] = (float)sin(ang);
    } else if (idx < 102310) {              // TABA
        int t = idx - 100980;
        int l = 0; while (l < 9 && t >= c_ZB1[l+1]) ++l;
        int L = 2*l + 1, loc = t - c_ZB1[l];
        ((int*)ws)[OFF_TABA + t] = l | ((loc / L) << 8) | ((loc % L) << 16);
    } else if (idx < 102596) {              // TABB
        int t = idx - 102310;
        int l = 0; while (l < 5 && t >= c_ZB2[l+1]) ++l;
        int L = 2*l + 1, loc = t - c_ZB2[l];
        ((int*)ws)[OFF_TABB + t] = l | ((loc / L) << 8) | ((loc % L) << 16);
    } else if (idx < 102796) {              // TH19 [a][mm]
        int e = idx - 102596; int a = e / 10, mm = e % 10;
        double f = (mm == 0) ? 1.0 : 2.0;
        double ang = 2.0 * PI * (double)(mm * a) / 20.0;
        ws[OFF_TH19 + 2*e]     = (float)(f * cos(ang));
        ws[OFF_TH19 + 2*e + 1] = (float)(f * sin(ang));
    } else if (idx < 102868) {              // TH12 [a][mm]
        int e = idx - 102796; int a = e / 6, mm = e % 6;
        double f = (mm == 0) ? 1.0 : 2.0;
        double ang = 2.0 * PI * (double)(mm * a) / 12.0;
        ws[OFF_TH12 + 2*e]     = (float)(f * cos(ang));
        ws[OFF_TH12 + 2*e + 1] = (float)(f * sin(ang));
    } else {                                // TABH: 146 half items (l|loc<<8)
        int t = idx - 102868;
        int l = 0, cum = 0, loc = 0;
        for (; l < 6; ++l) {
            int L = 2*l + 1, h = (L*L + 1) / 2;
            if (t < cum + h) { loc = t - cum; break; }
            cum += h;
        }
        ((int*)ws)[OFF_TABH + t] = l | (loc << 8);
    }
}

// ---------------- small pipeline kernels ----------------
__global__ void k_dft_alpha(const float* __restrict__ x, const float2* __restrict__ W60,
                            float2* __restrict__ xh) {
    int idx = blockIdx.x * blockDim.x + threadIdx.x;
    if (idx >= BT * 60 * 19) return;
    int r = idx % 19;
    int j = (idx / 19) % 60;
    int b = idx / (19 * 60);
    const float* xr = x + (b * 60 + j) * 60;
    const float2* wr = W60 + r * 60;
    float re = 0.f, im = 0.f;
    for (int a = 0; a < 60; ++a) {
        float v = xr[a];
        float2 w = wr[a];
        re += v * w.x; im += v * w.y;
    }
    xh[idx] = make_float2(re * (1.f / 60.f), im * (1.f / 60.f));
}

__global__ void k_X1(const float2* __restrict__ xh, const float* __restrict__ DM1,
                     float2* __restrict__ X) {
    int idx = blockIdx.x * blockDim.x + threadIdx.x;
    if (idx >= 100 * BT) return;
    int b = idx % BT, k = idx / BT;
    int l = 0; while ((l + 1) * (l + 1) <= k) ++l;
    int r = (k - l*l - l) + 9;
    float re = 0.f, im = 0.f;
    for (int j = 0; j < 60; ++j) {
        float d = DM1[k * 60 + j];
        float2 v = xh[(b * 60 + j) * 19 + r];
        re += d * v.x; im += d * v.y;
    }
    X[k * BT + b] = make_float2(re, im);
}

__global__ void k_Yk1(const float* __restrict__ k1, const float2* __restrict__ Y1B,
                      float2* __restrict__ Yk1) {
    int idx = blockIdx.x * blockDim.x + threadIdx.x;
    if (idx >= 100 * 20) return;
    int o = idx % 20, k = idx / 20;
    float re = 0.f, im = 0.f;
    for (int g = 0; g < 24; ++g) {
        float2 y = Y1B[k * 24 + g];
        float w = k1[o * 24 + g];
        re += y.x * w; im += y.y * w;
    }
    const float SC1 = 0.20412414523193154f;  // 1/sqrt(24)
    Yk1[idx] = make_float2(re * SC1, im * SC1);
}

// Yk2 layout: [o][k2][i]; one block per half-item, mirror written via Hermitian symmetry
__global__ __launch_bounds__(NT) void k_Yk2(const float* __restrict__ k2in,
                                            const float2* __restrict__ Y2B,
                                            const int* __restrict__ gTABH,
                                            float2* __restrict__ Yk2) {
    const int h = blockIdx.x;      // 0..145
    const int tid = threadIdx.x;
    int ph = gTABH[h];
    int l = ph & 255, loc = ph >> 8;
    int L = 2 * l + 1;
    int mi = loc / L, ni = loc % L;
    int k2  = c_ZB2[l] + loc;
    int locm = L * L - 1 - loc;
    int k2m = c_ZB2[l] + locm;
    float par = ((mi + ni) & 1) ? -1.f : 1.f;

    __shared__ __align__(16) float2 sY[192];
    for (int t = tid; t < 192; t += NT) sY[t] = Y2B[k2 * 192 + t];
    __syncthreads();
    const float4* sY4 = (const float4*)sY;
    const float SC2 = 0.016137430609197573f; // 1/sqrt(192*20)
    for (int t = tid; t < 800; t += NT) {
        int o = t / 20, i = t % 20;
        const float4* kp = (const float4*)(k2in + (i * 40 + o) * 192);
        float re = 0.f, im = 0.f;
        #pragma unroll 4
        for (int p = 0; p < 48; ++p) {
            float4 w = kp[p];
            float4 y01 = sY4[2*p], y23 = sY4[2*p + 1];
            re += w.x * y01.x + w.y * y01.z + w.z * y23.x + w.w * y23.z;
            im += w.x * y01.y + w.y * y01.w + w.z * y23.y + w.w * y23.w;
        }
        re *= SC2; im *= SC2;
        Yk2[(o * 286 + k2) * 20 + i] = make_float2(re, im);
        if (k2m != k2)
            Yk2[(o * 286 + k2m) * 20 + i] = make_float2(par * re, -par * im);
    }
}

// ---------------- stage 1: one block per (b,f1); wave-owned j; Hermitian-halved phases ----------------
// X2 layout: [b][k2][f1]
__global__ __launch_bounds__(NT) void k_stage1(
    const float2* __restrict__ X, const float2* __restrict__ Yk1,
    const float* __restrict__ gD1R, const float* __restrict__ gDM2,
    const float2* __restrict__ gT19, const float2* __restrict__ gT11,
    const float2* __restrict__ gTH19,
    const int* __restrict__ gTABA, const int* __restrict__ gTABB,
    float2* __restrict__ X2g) {
    const int b = blockIdx.x % BT;
    const int f = blockIdx.x / BT;   // 0..19
    const int tid = threadIdx.x;
    const int wv = tid >> 6, lane = tid & 63;

    __shared__ __align__(16) float2 sZ[1330];
    __shared__ __align__(16) float2 sX2w[4][286];
    __shared__ __align__(16) float2 sT19[440];   // [c][n], stride 22 (U phase)
    __shared__ __align__(16) float2 sTH19[240];  // [a][mm], stride 12 (x1 phase)
    __shared__ __align__(16) float2 sT11[220];   // [r][c], stride 20 (V/G phases, rows 5..10)
    __shared__ __align__(16) float2 sA[4][224];  // per-wave: S(10x22) | x1(400f) | G(66)
    __shared__ __align__(16) float2 sB[4][240];  // per-wave: U(20x12) | V(6x22)

    for (int t = tid; t < 380; t += NT) sT19[(t / 19) * 22 + (t % 19)] = gT19[t];
    for (int t = tid; t < 200; t += NT) sTH19[(t / 10) * 12 + (t % 10)] = gTH19[t];
    for (int t = tid; t < 220; t += NT) sT11[t] = gT11[t];
    for (int t = tid; t < 286; t += NT) {
        sX2w[0][t] = make_float2(0.f, 0.f); sX2w[1][t] = make_float2(0.f, 0.f);
        sX2w[2][t] = make_float2(0.f, 0.f); sX2w[3][t] = make_float2(0.f, 0.f);
    }
    for (int t = tid; t < 1330; t += NT) {
        int p = gTABA[t];
        int l = p & 255, mi = (p >> 8) & 255, ni = p >> 16;
        float2 a = X[(l*l + mi) * BT + b];
        float2 y = Yk1[(l*l + ni) * 20 + f];
        sZ[t] = make_float2(a.x * y.x + a.y * y.y, a.y * y.x - a.x * y.y);
    }
    __syncthreads();

    float2* S   = sA[wv];            // [mm][ni] mm=0..9, stride 22
    float2* U   = sB[wv];            // [c][mm] stride 12
    float*  x1  = (float*)sA[wv];    // [a][c] stride 20 floats
    float2* V   = sB[wv];            // [nn][a] nn=0..5, stride 22
    float2* G   = sA[wv];            // [mm][ni2] mm=0..5, stride 11
    float2* myX2 = sX2w[wv];

    for (int jj = 0; jj < 5; ++jj) {
        const int j = wv + 4 * jj;

        // ---- S[m][n], m=0..9 only (S[-m][-n]=conj(S[m][n]))
        {
            const float* dp = gD1R + j * 1330;
            for (int t = lane; t < 190; t += 64) {
                int mm = t / 19, ni = t % 19;
                int n = ni - 9;
                int an = n < 0 ? -n : n;
                int lmin = mm > an ? mm : an;
                float re = 0.f, im = 0.f;
                for (int l = lmin; l < 10; ++l) {
                    int L = 2*l + 1;
                    int o = c_ZB1[l] + (mm + l) * L + (n + l);
                    float dv = dp[o];
                    float2 z = sZ[o];
                    re += dv * z.x; im += dv * z.y;
                }
                S[mm * 22 + ni] = make_float2(re, im);
            }
        }
        wsync();

        // ---- U[m][c] = sum_n S[m][n] T19[c][n], m=0..9; write U[c][m]
        for (int t = lane; t < 200; t += 64) {
            int mm = t / 20, c = t % 20;
            const float4* sp = (const float4*)(S + mm * 22);
            const float4* tp = (const float4*)(sT19 + c * 22);
            float re = 0.f, im = 0.f;
            #pragma unroll
            for (int p = 0; p < 9; ++p) {
                float4 s = sp[p], w = tp[p];
                re += s.x * w.x - s.y * w.y + s.z * w.z - s.w * w.w;
                im += s.x * w.y + s.y * w.x + s.z * w.w + s.w * w.z;
            }
            float2 s1 = S[mm * 22 + 18], w1 = sT19[c * 22 + 18];
            re += s1.x * w1.x - s1.y * w1.y;
            im += s1.x * w1.y + s1.y * w1.x;
            U[c * 12 + mm] = make_float2(re, im);
        }
        wsync();

        // ---- x1[a][c] = sum_{mm=0..9} Re(U[mm][c] * TH19[a][mm]); relu
        for (int t = lane; t < 400; t += 64) {
            int a = t / 20, c = t % 20;
            const float4* up = (const float4*)(U + c * 12);
            const float4* tp = (const float4*)(sTH19 + a * 12);
            float a0 = 0.f, a1 = 0.f;
            #pragma unroll
            for (int p = 0; p < 5; ++p) {
                float4 u = up[p], w = tp[p];
                a0 += u.x * w.x - u.y * w.y;
                a1 += u.z * w.z - u.w * w.w;
            }
            float v = a0 + a1;
            x1[a * 20 + c] = v > 0.f ? v : 0.f;
        }
        wsync();

        // ---- V[nn][a] = sum_c x1[a][c] e^{-2pi i nn c/20}, nn=0..5 (V[-nn]=conj)
        for (int t = lane; t < 120; t += 64) {
            int nn = t / 20, a = t % 20;
            const float4* xp = (const float4*)(x1 + a * 20);
            const float4* tp = (const float4*)(sT11 + (nn + 5) * 20);
            float r0 = 0.f, i0 = 0.f, r1 = 0.f, i1 = 0.f;
            #pragma unroll
            for (int p = 0; p < 5; ++p) {
                float4 xv = xp[p];
                float4 t01 = tp[2*p], t23 = tp[2*p + 1];
                r0 += xv.x * t01.x + xv.y * t01.z;
                i0 += xv.x * t01.y + xv.y * t01.w;
                r1 += xv.z * t23.x + xv.w * t23.z;
                i1 += xv.z * t23.y + xv.w * t23.w;
            }
            V[nn * 22 + a] = make_float2(r0 + r1, i0 + i1);
        }
        wsync();

        // ---- G[mm][nn2], mm=0..5, nn2=-5..5; V[-n] = conj(V[n])
        for (int t = lane; t < 66; t += 64) {
            int mm = t / 11, ni2 = t % 11;
            int nn2 = ni2 - 5;
            int na = nn2 < 0 ? -nn2 : nn2;
            float s = nn2 < 0 ? -1.f : 1.f;
            const float4* vp = (const float4*)(V + na * 22);
            const float4* tp = (const float4*)(sT11 + (mm + 5) * 20);
            float r0 = 0.f, i0 = 0.f, r1 = 0.f, i1 = 0.f;
            #pragma unroll
            for (int q = 0; q < 10; ++q) {
                float4 v = vp[q], w = tp[q];
                float vy0 = s * v.y, vy1 = s * v.w;
                r0 += v.x * w.x - vy0 * w.y;
                i0 += v.x * w.y + vy0 * w.x;
                r1 += v.z * w.z - vy1 * w.w;
                i1 += v.z * w.w + vy1 * w.z;
            }
            G[mm * 11 + ni2] = make_float2(r0 + r1, i0 + i1);
        }
        wsync();

        // ---- X2w[k2] += DM2[j][k2] * G (negatives via conj)
        {
            const float* dmp = gDM2 + j * 286;
            for (int k2 = lane; k2 < 286; k2 += 64) {
                int p = gTABB[k2];
                int l = p & 255, mi = (p >> 8) & 255, ni = p >> 16;
                int m = mi - l, n = ni - l;
                int gi; float sg;
                if (m >= 0) { gi = m * 11 + (n + 5); sg = 1.f; }
                else        { gi = (-m) * 11 + (5 - n); sg = -1.f; }
                float dm = dmp[k2];
                float2 g = G[gi];
                myX2[k2].x += dm * g.x;
                myX2[k2].y += dm * sg * g.y;
            }
        }
        wsync();
    }
    __syncthreads();

    for (int t = tid; t < 286; t += NT) {
        float2 v0 = sX2w[0][t], v1 = sX2w[1][t], v2 = sX2w[2][t], v3 = sX2w[3][t];
        X2g[b * 5720 + t * 20 + f] =
            make_float2((v0.x + v1.x + v2.x + v3.x) * (1.f / 400.f),
                        (v0.y + v1.y + v2.y + v3.y) * (1.f / 400.f));
    }
}

// ---------------- stage 2a: Z half-items + Hermitian mirror ----------------
__global__ __launch_bounds__(NT) void k_Z2(
    const float2* __restrict__ X2g, const float2* __restrict__ Yk2,
    const int* __restrict__ gTABB, const int* __restrict__ gTABH,
    float2* __restrict__ Z2g) {
    const int bt = blockIdx.x & 7;        // 0..7
    const int o  = blockIdx.x >> 3;       // 0..39
    const int b0 = bt * 16;
    const int tid = threadIdx.x;

    __shared__ __align__(16) float2 sB[5792];

    const float2* Bg = Yk2 + o * 5720;
    for (int e = tid; e < 5720; e += NT) {
        int k2 = e / 20, i = e % 20;
        int p = gTABB[k2];
        int l = p & 255, r = (p >> 8) & 255, kk = p >> 16;
        sB[c_BOFF[l] + r * (40 * l + 22) + kk * 20 + i] = Bg[e];
    }
    __syncthreads();

    for (int q = tid; q < 16 * 146; q += NT) {
        int b_local = q / 146, h = q % 146;
        int ph = gTABH[h];
        int l = ph & 255, loc = ph >> 8;
        int L = 2 * l + 1;
        int mi = loc / L, ni = loc % L;
        const float4* ap = (const float4*)(X2g + (size_t)(b0 + b_local) * 5720
                                           + (c_ZB2[l] + mi * L) * 20);
        const float4* bp = (const float4*)(sB + c_BOFF[l] + ni * (40 * l + 22));
        float re = 0.f, im = 0.f;
        int n4 = 10 * L;
        for (int p4 = 0; p4 < n4; ++p4) {
            float4 a = ap[p4], y = bp[p4];
            re += a.x * y.x + a.y * y.y + a.z * y.z + a.w * y.w;
            im += a.y * y.x - a.x * y.y + a.w * y.z - a.z * y.w;
        }
        size_t base = ((size_t)(b0 + b_local) * 40 + o) * 286;
        Z2g[base + c_ZB2[l] + loc] = make_float2(re, im);
        int locm = L * L - 1 - loc;
        if (locm != loc) {
            float sg = ((mi + ni) & 1) ? -1.f : 1.f;
            Z2g[base + c_ZB2[l] + locm] = make_float2(sg * re, -sg * im);
        }
    }
}

// ---------------- stage 2b: Hermitian-halved j-loop + integrate ----------------
__global__ __launch_bounds__(NT) void k_stage2b(
    const float2* __restrict__ Z2g, const float* __restrict__ gD2R,
    const float2* __restrict__ gT12, const float2* __restrict__ gTH12,
    const float* __restrict__ gW2J, float* __restrict__ feat) {
    const int b = blockIdx.x % BT;
    const int o = blockIdx.x / BT;   // 0..39
    const int tid = threadIdx.x;
    const int wv = tid >> 6, lane = tid & 63;

    __shared__ __align__(16) float2 sZb[286];
    __shared__ __align__(16) float2 sT12[168];   // [c][n], stride 14
    __shared__ __align__(16) float2 sTH12[96];   // [a][mm], stride 8
    __shared__ __align__(16) float2 sS[4][88];   // [mm][ni] mm=0..5, stride 14
    __shared__ __align__(16) float2 sU[4][96];   // [c][mm], stride 8
    __shared__ float sredw[4];

    const float2* Zr = Z2g + ((size_t)b * 40 + o) * 286;
    for (int t = tid; t < 286; t += NT) sZb[t] = Zr[t];
    for (int t = tid; t < 132; t += NT) sT12[(t / 11) * 14 + (t % 11)] = gT12[t];
    for (int t = tid; t < 72; t += NT) sTH12[(t / 6) * 8 + (t % 6)] = gTH12[t];
    __syncthreads();

    float2* S = sS[wv];
    float2* U = sU[wv];
    float facc = 0.f;

    for (int jj = 0; jj < 3; ++jj) {
        const int j = wv + 4 * jj;

        // ---- S2[m][n], m=0..5 only
        {
            const float* dp = gD2R + j * 286;
            for (int t = lane; t < 66; t += 64) {
                int mm = t / 11, ni = t % 11;
                int n = ni - 5;
                int an = n < 0 ? -n : n;
                int lmin = mm > an ? mm : an;
                float re = 0.f, im = 0.f;
                for (int l = lmin; l < 6; ++l) {
                    int L = 2*l + 1;
                    int off = c_ZB2[l] + (mm + l) * L + (n + l);
                    float dv = dp[off];
                    float2 z = sZb[off];
                    re += dv * z.x; im += dv * z.y;
                }
                S[mm * 14 + ni] = make_float2(re, im);
            }
        }
        wsync();

        // ---- U2[m][c] = sum_n S2[m][n] T12[c][n], m=0..5; write U[c][m]
        for (int t = lane; t < 72; t += 64) {
            int mm = t / 12, c = t % 12;
            const float4* sp = (const float4*)(S + mm * 14);
            const float4* tp = (const float4*)(sT12 + c * 14);
            float re = 0.f, im = 0.f;
            #pragma unroll
            for (int p = 0; p < 5; ++p) {
                float4 s = sp[p], w = tp[p];
                re += s.x * w.x - s.y * w.y + s.z * w.z - s.w * w.w;
                im += s.x * w.y + s.y * w.x + s.z * w.w + s.w * w.z;
            }
            float2 s1 = S[mm * 14 + 10], w1 = sT12[c * 14 + 10];
            re += s1.x * w1.x - s1.y * w1.y;
            im += s1.x * w1.y + s1.y * w1.x;
            U[c * 8 + mm] = make_float2(re, im);
        }
        wsync();

        // ---- x2[a][c] = sum_{mm=0..5} Re(U2[mm][c]*TH12[a][mm]); relu; integrate
        {
            float wj = gW2J[j];
            for (int t = lane; t < 144; t += 64) {
                int a = t / 12, c = t % 12;
                const float4* up = (const float4*)(U + c * 8);
                const float4* tp = (const float4*)(sTH12 + a * 8);
                float acc = 0.f;
                #pragma unroll
                for (int p = 0; p < 3; ++p) {
                    float4 u = up[p], w = tp[p];
                    acc += u.x * w.x - u.y * w.y + u.z * w.z - u.w * w.w;
                }
                if (acc > 0.f) facc += wj * acc;
            }
        }
        wsync();
    }

    #pragma unroll
    for (int d = 32; d > 0; d >>= 1) facc += __shfl_down(facc, d, 64);
    if (lane == 0) sredw[wv] = facc;
    __syncthreads();
    if (tid == 0) {
        const float INTEG = 0.27415567780803774f;  // (2*pi/12)^2
        feat[b * 40 + o] = (sredw[0] + sredw[1] + sredw[2] + sredw[3]) * INTEG;
    }
}

__global__ void k_out(const float* __restrict__ feat, const float* __restrict__ w,
                      const float* __restrict__ bias, float* __restrict__ out) {
    int idx = blockIdx.x * blockDim.x + threadIdx.x;
    if (idx >= BT * 10) return;
    int fo = idx % 10, b = idx / 10;
    float acc = bias[fo];
    for (int o2 = 0; o2 < 40; ++o2) acc += feat[b * 40 + o2] * w[fo * 40 + o2];
    out[idx] = acc;
}

extern "C" void kernel_launch(void* const* d_in, const int* in_sizes, int n_in,
                              void* d_out, int out_size, void* d_ws, size_t ws_size,
                              hipStream_t stream) {
    (void)in_sizes; (void)n_in; (void)out_size; (void)ws_size;
    const float* x   = (const float*)d_in[0];
    const float* k1  = (const float*)d_in[1];
    const float* k2  = (const float*)d_in[2];
    const float* wO  = (const float*)d_in[3];
    const float* bO  = (const float*)d_in[4];
    float* out = (float*)d_out;

    float* ws = (float*)d_ws;
    const float2* cW60 = (const float2*)(ws + OFF_W60);
    const float*  cW2J = ws + OFF_W2J;
    const float*  cDM1 = ws + OFF_DM1;
    const float2* cY1B = (const float2*)(ws + OFF_Y1B);
    const float*  gD1R = ws + OFF_D1R;
    const float*  gDM2 = ws + OFF_DM2;
    const float2* cY2B = (const float2*)(ws + OFF_Y2B);
    const float*  gD2R = ws + OFF_D2R;
    const float2* gT19 = (const float2*)(ws + OFF_T19U);
    const float2* gT11 = (const float2*)(ws + OFF_T11V);
    const float2* gT12 = (const float2*)(ws + OFF_T12U);
    const float2* gTH19 = (const float2*)(ws + OFF_TH19);
    const float2* gTH12 = (const float2*)(ws + OFF_TH12);
    const int*    gTABA = (const int*)(ws + OFF_TABA);
    const int*    gTABB = (const int*)(ws + OFF_TABB);
    const int*    gTABH = (const int*)(ws + OFF_TABH);

    float2* xh   = (float2*)(ws + OFF_END);          // 128*60*19
    float2* X    = xh + BT * 60 * 19;                // 100*128
    float2* Yk1  = X + 100 * BT;                     // 100*20
    float2* Yk2  = Yk1 + 100 * 20;                   // 40*286*20
    float2* X2   = Yk2 + 40 * 286 * 20;              // 128*286*20  [b][k2][i]
    float*  feat = (float*)(X2 + (size_t)BT * 5720); // 128*40
    float2* Z2   = (float2*)(feat + BT * 40);        // 128*40*286

    k_init<<<(N_INIT + NT - 1) / NT, NT, 0, stream>>>(ws);
    k_dft_alpha<<<(BT * 60 * 19 + NT - 1) / NT, NT, 0, stream>>>(x, cW60, xh);
    k_X1<<<(100 * BT + NT - 1) / NT, NT, 0, stream>>>(xh, cDM1, X);
    k_Yk1<<<(100 * 20 + NT - 1) / NT, NT, 0, stream>>>(k1, cY1B, Yk1);
    k_Yk2<<<146, NT, 0, stream>>>(k2, cY2B, gTABH, Yk2);
    k_stage1<<<BT * 20, NT, 0, stream>>>(X, Yk1, gD1R, gDM2, gT19, gT11, gTH19, gTABA, gTABB, X2);
    k_Z2<<<320, NT, 0, stream>>>(X2, Yk2, gTABB, gTABH, Z2);
    k_stage2b<<<BT * 40, NT, 0, stream>>>(Z2, gD2R, gT12, gTH12, cW2J, feat);
    k_out<<<(BT * 10 + NT - 1) / NT, NT, 0, stream>>>(feat, wO, bO, out);
}

// Round 7
// 505.884 us; speedup vs baseline: 2.2589x; 1.0784x over previous
//
#include <hip/hip_runtime.h>
#include <cmath>

#define NT 256
#define BT 128

// ---------------- ws float-offsets for constant tables ----------------
#define OFF_W60   0          // 19*60 complex
#define OFF_E20   2280       // legacy
#define OFF_E12   2320       // legacy
#define OFF_W2J   2344       // 12 floats
#define OFF_DM1   2356       // 100*60
#define OFF_Y1B   8356       // 100*24 complex
#define OFF_D1R   13156      // [j=20][flat=1330] (2l+1)*d^l at beta1
#define OFF_DM2   39756      // [j=20][k2=286]  w1[j]*d^l(beta1_j)
#define OFF_Y2B   45476      // 286*192 complex
#define OFF_D2R   155300     // [j=12][flat=286] (2l+1)*d^l at beta2
#define OFF_T19U  158732     // 20x19 complex [c][n] e^{+2pi i n c/20}
#define OFF_T11V  159492     // 11x20 complex [r][c] e^{-2pi i (r-5) c/20}
#define OFF_T12U  159932     // 12x11 complex [c][n] e^{+2pi i n c/12}
#define OFF_TABA  160196     // 1330 int packed (legacy, full Z table)
#define OFF_TABB  161526     // 286 int packed
#define OFF_TH19  161812     // 20x10 complex [a][mm] f*e^{+2pi i mm a/20}, f=1 (mm=0) else 2
#define OFF_TH12  162212     // 12x6 complex [a][mm] f*e^{+2pi i mm a/12}
#define OFF_TABH  162356     // 146 int packed (l | loc<<8): half items per l
#define OFF_TAH1  162504     // 715 int packed (l | mm<<8 | ni<<16): upper-half Z items
#define OFF_END   163220
#define N_INIT    103729

__constant__ int c_ZB1[10] = {0,1,10,35,84,165,286,455,680,969};
__constant__ int c_ZBH[10] = {0,1,7,22,50,95,161,252,372,525};  // upper-half Z offsets, total 715
__constant__ int c_ZB2[6]  = {0,1,10,35,84,165};
__constant__ int c_BOFF[6] = {0,22,208,718,1712,3350};  // padded row offsets for k_Z2 LDS

// wave-local sync: per-wave-private LDS phase buffers only.
__device__ inline void wsync() {
    __asm__ volatile("" ::: "memory");
    __builtin_amdgcn_s_waitcnt(0xC07F);   // vmcnt=63, expcnt=7, lgkmcnt=0
    __builtin_amdgcn_wave_barrier();
    __asm__ volatile("" ::: "memory");
}

// ---------------- fp64 helpers for the init kernel ----------------
__device__ inline double dipow(double x, int e) {
    double r = 1.0;
    for (int i = 0; i < e; ++i) r *= x;
    return r;
}

__device__ double wigd(const double* F, int l, int mp, int m, double beta) {
    double cb = cos(beta * 0.5), sb = sin(beta * 0.5);
    int smin = m - mp; if (smin < 0) smin = 0;
    int smax = l + m;  if (l - mp < smax) smax = l - mp;
    double pref = sqrt(F[l+mp] * F[l-mp] * F[l+m] * F[l-m]);
    double sum = 0.0;
    for (int s = smin; s <= smax; ++s) {
        double t = pref / (F[l+m-s] * F[s] * F[mp-m+s] * F[l-mp-s]);
        t *= dipow(cb, 2*l + m - mp - 2*s) * dipow(sb, mp - m + 2*s);
        sum += ((mp - m + s) & 1) ? -t : t;
    }
    return sum;
}

__device__ double qwj(int bnd, int j) {
    const double PI = 3.14159265358979323846;
    double theta = PI * (2*j + 1) / (4.0 * bnd);
    double s = 0.0;
    for (int k = 0; k < bnd; ++k) s += sin(theta * (2*k + 1)) / (2*k + 1);
    return 2.0 / bnd * sin(theta) * s;
}

// ---------------- init ----------------
__global__ void k_init(float* __restrict__ ws) {
    int idx = blockIdx.x * blockDim.x + threadIdx.x;
    if (idx >= N_INIT) return;
    double F[20];
    F[0] = 1.0;
    #pragma unroll
    for (int i = 1; i < 20; ++i) F[i] = F[i-1] * i;
    const double PI = 3.14159265358979323846;

    if (idx < 1140) {                       // W60
        int r = idx / 60, a = idx % 60;
        double ang = -2.0 * PI * (double)((r - 9) * a) / 60.0;
        ws[OFF_W60 + 2*idx]     = (float)cos(ang);
        ws[OFF_W60 + 2*idx + 1] = (float)sin(ang);
    } else if (idx < 1160) {
        int t = idx - 1140;
        double ang = 2.0 * PI * t / 20.0;
        ws[OFF_E20 + 2*t]     = (float)cos(ang);
        ws[OFF_E20 + 2*t + 1] = (float)sin(ang);
    } else if (idx < 1172) {
        int t = idx - 1160;
        double ang = 2.0 * PI * t / 12.0;
        ws[OFF_E12 + 2*t]     = (float)cos(ang);
        ws[OFF_E12 + 2*t + 1] = (float)sin(ang);
    } else if (idx < 1184) {                // W2J
        int j = idx - 1172;
        ws[OFF_W2J + j] = (float)qwj(6, j);
    } else if (idx < 7184) {                // DM1[k][j]
        int e = idx - 1184; int k = e / 60, j = e % 60;
        int l = 0; while ((l + 1) * (l + 1) <= k) ++l;
        int m = k - l*l - l;
        double beta = PI * (2*j + 1) / 120.0;
        ws[OFF_DM1 + e] = (float)(qwj(30, j) * wigd(F, l, m, 0, beta));
    } else if (idx < 9584) {                // Y1B
        int e = idx - 7184; int k = e / 24, g = e % 24;
        int l = 0; while ((l + 1) * (l + 1) <= k) ++l;
        int m = k - l*l - l;
        int bi = g / 8, ai = g % 8;
        double beta  = (bi + 1) * (PI / 8.0) / 3.0;
        double alpha = 2.0 * PI * ai / 8.0;
        double d = wigd(F, l, m, 0, beta);
        double ph = -(double)m * alpha;
        ws[OFF_Y1B + 2*e]     = (float)(d * cos(ph));
        ws[OFF_Y1B + 2*e + 1] = (float)(d * sin(ph));
    } else if (idx < 36184) {               // D1R [j][flat], prescaled by (2l+1)
        int e = idx - 9584; int j = e / 1330, t = e % 1330;
        int l = 0; while (l < 9 && t >= c_ZB1[l+1]) ++l;
        int L = 2*l + 1, loc = t - c_ZB1[l];
        int mi = loc / L, ni = loc % L;
        double beta = PI * (2*j + 1) / 40.0;
        ws[OFF_D1R + e] = (float)((double)L * wigd(F, l, mi - l, ni - l, beta));
    } else if (idx < 41904) {               // DM2 [j][k2]
        int e = idx - 36184; int j = e / 286, k2 = e % 286;
        int l = 0; while (l < 5 && k2 >= c_ZB2[l+1]) ++l;
        int L = 2*l + 1, loc = k2 - c_ZB2[l];
        int mi = loc / L, ni = loc % L;
        double beta = PI * (2*j + 1) / 40.0;
        ws[OFF_DM2 + e] = (float)(qwj(10, j) * wigd(F, l, mi - l, ni - l, beta));
    } else if (idx < 96816) {               // Y2B
        int e = idx - 41904; int k2 = e / 192, g = e % 192;
        int l = 0; while (l < 5 && k2 >= c_ZB2[l+1]) ++l;
        int L = 2*l + 1, loc = k2 - c_ZB2[l];
        int m = loc / L - l, n = loc % L - l;
        int bi = g / 64, ai = (g / 8) % 8, ci = g % 8;
        double beta  = (bi + 1) * (PI / 8.0) / 3.0;
        double alpha = 2.0 * PI * ai / 8.0;
        double gamma = (-2.0 * PI + ci * (PI / 2.0)) - alpha;
        double d = wigd(F, l, m, n, beta);
        double ph = -((double)m * alpha + (double)n * gamma);
        ws[OFF_Y2B + 2*e]     = (float)(d * cos(ph));
        ws[OFF_Y2B + 2*e + 1] = (float)(d * sin(ph));
    } else if (idx < 100248) {              // D2R [j][flat], prescaled by (2l+1)
        int e = idx - 96816; int j = e / 286, t = e % 286;
        int l = 0; while (l < 5 && t >= c_ZB2[l+1]) ++l;
        int L = 2*l + 1, loc = t - c_ZB2[l];
        int mi = loc / L, ni = loc % L;
        double beta = PI * (2*j + 1) / 24.0;
        ws[OFF_D2R + e] = (float)((double)L * wigd(F, l, mi - l, ni - l, beta));
    } else if (idx < 100628) {              // T19U [c][n]
        int e = idx - 100248; int c = e / 19, n = e % 19 - 9;
        double ang = 2.0 * PI * (double)(n * c) / 20.0;
        ws[OFF_T19U + 2*e]     = (float)cos(ang);
        ws[OFF_T19U + 2*e + 1] = (float)sin(ang);
    } else if (idx < 100848) {              // T11V [r][c]
        int e = idx - 100628; int r = e / 20, c = e % 20;
        double ang = -2.0 * PI * (double)((r - 5) * c) / 20.0;
        ws[OFF_T11V + 2*e]     = (float)cos(ang);
        ws[OFF_T11V + 2*e + 1] = (float)sin(ang);
    } else if (idx < 100980) {              // T12U [c][n]
        int e = idx - 100848; int c = e / 11, n = e % 11 - 5;
        double ang = 2.0 * PI * (double)(n * c) / 12.0;
        ws[OFF_T12U + 2*e]     = (float)cos(ang);
        ws[OFF_T12U + 2*e + 1] = (float)sin(ang);
    } else if (idx < 102310) {              // TABA (legacy full table)
        int t = idx - 100980;
        int l = 0; while (l < 9 && t >= c_ZB1[l+1]) ++l;
        int L = 2*l + 1, loc = t - c_ZB1[l];
        ((int*)ws)[OFF_TABA + t] = l | ((loc / L) << 8) | ((loc % L) << 16);
    } else if (idx < 102596) {              // TABB
        int t = idx - 102310;
        int l = 0; while (l < 5 && t >= c_ZB2[l+1]) ++l;
        int L = 2*l + 1, loc = t - c_ZB2[l];
        ((int*)ws)[OFF_TABB + t] = l | ((loc / L) << 8) | ((loc % L) << 16);
    } else if (idx < 102796) {              // TH19 [a][mm]
        int e = idx - 102596; int a = e / 10, mm = e % 10;
        double f = (mm == 0) ? 1.0 : 2.0;
        double ang = 2.0 * PI * (double)(mm * a) / 20.0;
        ws[OFF_TH19 + 2*e]     = (float)(f * cos(ang));
        ws[OFF_TH19 + 2*e + 1] = (float)(f * sin(ang));
    } else if (idx < 102868) {              // TH12 [a][mm]
        int e = idx - 102796; int a = e / 6, mm = e % 6;
        double f = (mm == 0) ? 1.0 : 2.0;
        double ang = 2.0 * PI * (double)(mm * a) / 12.0;
        ws[OFF_TH12 + 2*e]     = (float)(f * cos(ang));
        ws[OFF_TH12 + 2*e + 1] = (float)(f * sin(ang));
    } else if (idx < 103014) {              // TABH: 146 half items (l|loc<<8)
        int t = idx - 102868;
        int l = 0, cum = 0, loc = 0;
        for (; l < 6; ++l) {
            int L = 2*l + 1, h = (L*L + 1) / 2;
            if (t < cum + h) { loc = t - cum; break; }
            cum += h;
        }
        ((int*)ws)[OFF_TABH + t] = l | (loc << 8);
    } else {                                // TAH1: 715 upper-half Z items (l|mm<<8|ni<<16)
        int t = idx - 103014;
        int l = 0; while (l < 9 && t >= c_ZBH[l+1]) ++l;
        int L = 2*l + 1, loc = t - c_ZBH[l];
        ((int*)ws)[OFF_TAH1 + t] = l | ((loc / L) << 8) | ((loc % L) << 16);
    }
}

// ---------------- small pipeline kernels ----------------
__global__ void k_dft_alpha(const float* __restrict__ x, const float2* __restrict__ W60,
                            float2* __restrict__ xh) {
    int idx = blockIdx.x * blockDim.x + threadIdx.x;
    if (idx >= BT * 60 * 19) return;
    int r = idx % 19;
    int j = (idx / 19) % 60;
    int b = idx / (19 * 60);
    const float* xr = x + (b * 60 + j) * 60;
    const float2* wr = W60 + r * 60;
    float re = 0.f, im = 0.f;
    for (int a = 0; a < 60; ++a) {
        float v = xr[a];
        float2 w = wr[a];
        re += v * w.x; im += v * w.y;
    }
    xh[idx] = make_float2(re * (1.f / 60.f), im * (1.f / 60.f));
}

__global__ void k_X1(const float2* __restrict__ xh, const float* __restrict__ DM1,
                     float2* __restrict__ X) {
    int idx = blockIdx.x * blockDim.x + threadIdx.x;
    if (idx >= 100 * BT) return;
    int b = idx % BT, k = idx / BT;
    int l = 0; while ((l + 1) * (l + 1) <= k) ++l;
    int r = (k - l*l - l) + 9;
    float re = 0.f, im = 0.f;
    for (int j = 0; j < 60; ++j) {
        float d = DM1[k * 60 + j];
        float2 v = xh[(b * 60 + j) * 19 + r];
        re += d * v.x; im += d * v.y;
    }
    X[k * BT + b] = make_float2(re, im);
}

__global__ void k_Yk1(const float* __restrict__ k1, const float2* __restrict__ Y1B,
                      float2* __restrict__ Yk1) {
    int idx = blockIdx.x * blockDim.x + threadIdx.x;
    if (idx >= 100 * 20) return;
    int o = idx % 20, k = idx / 20;
    float re = 0.f, im = 0.f;
    for (int g = 0; g < 24; ++g) {
        float2 y = Y1B[k * 24 + g];
        float w = k1[o * 24 + g];
        re += y.x * w; im += y.y * w;
    }
    const float SC1 = 0.20412414523193154f;  // 1/sqrt(24)
    Yk1[idx] = make_float2(re * SC1, im * SC1);
}

// Yk2 layout: [o][k2][i]; one block per half-item, mirror written via Hermitian symmetry
__global__ __launch_bounds__(NT) void k_Yk2(const float* __restrict__ k2in,
                                            const float2* __restrict__ Y2B,
                                            const int* __restrict__ gTABH,
                                            float2* __restrict__ Yk2) {
    const int h = blockIdx.x;      // 0..145
    const int tid = threadIdx.x;
    int ph = gTABH[h];
    int l = ph & 255, loc = ph >> 8;
    int L = 2 * l + 1;
    int mi = loc / L, ni = loc % L;
    int k2  = c_ZB2[l] + loc;
    int locm = L * L - 1 - loc;
    int k2m = c_ZB2[l] + locm;
    float par = ((mi + ni) & 1) ? -1.f : 1.f;

    __shared__ __align__(16) float2 sY[192];
    for (int t = tid; t < 192; t += NT) sY[t] = Y2B[k2 * 192 + t];
    __syncthreads();
    const float4* sY4 = (const float4*)sY;
    const float SC2 = 0.016137430609197573f; // 1/sqrt(192*20)
    for (int t = tid; t < 800; t += NT) {
        int o = t / 20, i = t % 20;
        const float4* kp = (const float4*)(k2in + (i * 40 + o) * 192);
        float re = 0.f, im = 0.f;
        #pragma unroll 4
        for (int p = 0; p < 48; ++p) {
            float4 w = kp[p];
            float4 y01 = sY4[2*p], y23 = sY4[2*p + 1];
            re += w.x * y01.x + w.y * y01.z + w.z * y23.x + w.w * y23.z;
            im += w.x * y01.y + w.y * y01.w + w.z * y23.y + w.w * y23.w;
        }
        re *= SC2; im *= SC2;
        Yk2[(o * 286 + k2) * 20 + i] = make_float2(re, im);
        if (k2m != k2)
            Yk2[(o * 286 + k2m) * 20 + i] = make_float2(par * re, -par * im);
    }
}

// ---------------- stage 1: one block per (b,f1); wave-owned j; Hermitian-halved; slim LDS ----------------
// X2 layout: [b][k2][f1]
__global__ __launch_bounds__(NT, 5) void k_stage1(
    const float2* __restrict__ X, const float2* __restrict__ Yk1,
    const float* __restrict__ gD1R, const float* __restrict__ gDM2,
    const float2* __restrict__ gT19, const float2* __restrict__ gT11,
    const float2* __restrict__ gTH19,
    const int* __restrict__ gTAH1, const int* __restrict__ gTABB,
    float2* __restrict__ X2g) {
    const int b = blockIdx.x % BT;
    const int f = blockIdx.x / BT;   // 0..19
    const int tid = threadIdx.x;
    const int wv = tid >> 6, lane = tid & 63;

    __shared__ __align__(16) float2 sZ[715];     // upper-half rows only (mi >= l)
    __shared__ __align__(16) float2 sX2[286];
    __shared__ __align__(16) float2 sT19[440];   // [c][n], stride 22 (U phase)
    __shared__ __align__(16) float2 sTH19[240];  // [a][mm], stride 12 (x1 phase)
    __shared__ __align__(16) float2 sT11[220];   // [r][c], stride 20 (V/G phases, rows 5..10)
    __shared__ __align__(16) float2 sA[4][224];  // per-wave: S(10x22) | x1(400f) | G(66)
    __shared__ __align__(16) float2 sB[4][240];  // per-wave: U(20x12) | V(6x22)

    for (int t = tid; t < 380; t += NT) sT19[(t / 19) * 22 + (t % 19)] = gT19[t];
    for (int t = tid; t < 200; t += NT) sTH19[(t / 10) * 12 + (t % 10)] = gTH19[t];
    for (int t = tid; t < 220; t += NT) sT11[t] = gT11[t];
    for (int t = tid; t < 286; t += NT) sX2[t] = make_float2(0.f, 0.f);
    for (int t = tid; t < 715; t += NT) {
        int p = gTAH1[t];
        int l = p & 255, mm = (p >> 8) & 255, ni = p >> 16;
        float2 a = X[(l*l + l + mm) * BT + b];
        float2 y = Yk1[(l*l + ni) * 20 + f];
        sZ[t] = make_float2(a.x * y.x + a.y * y.y, a.y * y.x - a.x * y.y);
    }
    __syncthreads();

    float2* S   = sA[wv];            // [mm][ni] mm=0..9, stride 22
    float2* U   = sB[wv];            // [c][mm] stride 12
    float*  x1  = (float*)sA[wv];    // [a][c] stride 20 floats
    float2* V   = sB[wv];            // [nn][a] nn=0..5, stride 22
    float2* G   = sA[wv];            // [mm][ni2] mm=0..5, stride 11

    float2 x2acc[5];
    #pragma unroll
    for (int i = 0; i < 5; ++i) x2acc[i] = make_float2(0.f, 0.f);

    for (int jj = 0; jj < 5; ++jj) {
        const int j = wv + 4 * jj;

        // ---- S[m][n], m=0..9 only (S[-m][-n]=conj(S[m][n])); Z from half store
        {
            const float* dp = gD1R + j * 1330;
            for (int t = lane; t < 190; t += 64) {
                int mm = t / 19, ni = t % 19;
                int n = ni - 9;
                int an = n < 0 ? -n : n;
                int lmin = mm > an ? mm : an;
                float re = 0.f, im = 0.f;
                for (int l = lmin; l < 10; ++l) {
                    int L = 2*l + 1;
                    float dv = dp[c_ZB1[l] + (mm + l) * L + (n + l)];
                    float2 z = sZ[c_ZBH[l] + mm * L + (n + l)];
                    re += dv * z.x; im += dv * z.y;
                }
                S[mm * 22 + ni] = make_float2(re, im);
            }
        }
        wsync();

        // ---- U[m][c] = sum_n S[m][n] T19[c][n], m=0..9; write U[c][m]
        for (int t = lane; t < 200; t += 64) {
            int mm = t / 20, c = t % 20;
            const float4* sp = (const float4*)(S + mm * 22);
            const float4* tp = (const float4*)(sT19 + c * 22);
            float re = 0.f, im = 0.f;
            #pragma unroll
            for (int p = 0; p < 9; ++p) {
                float4 s = sp[p], w = tp[p];
                re += s.x * w.x - s.y * w.y + s.z * w.z - s.w * w.w;
                im += s.x * w.y + s.y * w.x + s.z * w.w + s.w * w.z;
            }
            float2 s1 = S[mm * 22 + 18], w1 = sT19[c * 22 + 18];
            re += s1.x * w1.x - s1.y * w1.y;
            im += s1.x * w1.y + s1.y * w1.x;
            U[c * 12 + mm] = make_float2(re, im);
        }
        wsync();

        // ---- x1[a][c] = sum_{mm=0..9} Re(U[mm][c] * TH19[a][mm]); relu
        for (int t = lane; t < 400; t += 64) {
            int a = t / 20, c = t % 20;
            const float4* up = (const float4*)(U + c * 12);
            const float4* tp = (const float4*)(sTH19 + a * 12);
            float a0 = 0.f, a1 = 0.f;
            #pragma unroll
            for (int p = 0; p < 5; ++p) {
                float4 u = up[p], w = tp[p];
                a0 += u.x * w.x - u.y * w.y;
                a1 += u.z * w.z - u.w * w.w;
            }
            float v = a0 + a1;
            x1[a * 20 + c] = v > 0.f ? v : 0.f;
        }
        wsync();

        // ---- V[nn][a] = sum_c x1[a][c] e^{-2pi i nn c/20}, nn=0..5 (V[-nn]=conj)
        for (int t = lane; t < 120; t += 64) {
            int nn = t / 20, a = t % 20;
            const float4* xp = (const float4*)(x1 + a * 20);
            const float4* tp = (const float4*)(sT11 + (nn + 5) * 20);
            float r0 = 0.f, i0 = 0.f, r1 = 0.f, i1 = 0.f;
            #pragma unroll
            for (int p = 0; p < 5; ++p) {
                float4 xv = xp[p];
                float4 t01 = tp[2*p], t23 = tp[2*p + 1];
                r0 += xv.x * t01.x + xv.y * t01.z;
                i0 += xv.x * t01.y + xv.y * t01.w;
                r1 += xv.z * t23.x + xv.w * t23.z;
                i1 += xv.z * t23.y + xv.w * t23.w;
            }
            V[nn * 22 + a] = make_float2(r0 + r1, i0 + i1);
        }
        wsync();

        // ---- G[mm][nn2], mm=0..5, nn2=-5..5; V[-n] = conj(V[n])
        for (int t = lane; t < 66; t += 64) {
            int mm = t / 11, ni2 = t % 11;
            int nn2 = ni2 - 5;
            int na = nn2 < 0 ? -nn2 : nn2;
            float s = nn2 < 0 ? -1.f : 1.f;
            const float4* vp = (const float4*)(V + na * 22);
            const float4* tp = (const float4*)(sT11 + (mm + 5) * 20);
            float r0 = 0.f, i0 = 0.f, r1 = 0.f, i1 = 0.f;
            #pragma unroll
            for (int q = 0; q < 10; ++q) {
                float4 v = vp[q], w = tp[q];
                float vy0 = s * v.y, vy1 = s * v.w;
                r0 += v.x * w.x - vy0 * w.y;
                i0 += v.x * w.y + vy0 * w.x;
                r1 += v.z * w.z - vy1 * w.w;
                i1 += v.z * w.w + vy1 * w.z;
            }
            G[mm * 11 + ni2] = make_float2(r0 + r1, i0 + i1);
        }
        wsync();

        // ---- x2acc[i] += DM2[j][k2] * G (negatives via conj); registers, no LDS
        {
            const float* dmp = gDM2 + j * 286;
            #pragma unroll
            for (int i = 0; i < 5; ++i) {
                int k2 = lane + 64 * i;
                if (k2 < 286) {
                    int p = gTABB[k2];
                    int l = p & 255, mi = (p >> 8) & 255, ni = p >> 16;
                    int m = mi - l, n = ni - l;
                    int gi; float sg;
                    if (m >= 0) { gi = m * 11 + (n + 5); sg = 1.f; }
                    else        { gi = (-m) * 11 + (5 - n); sg = -1.f; }
                    float dm = dmp[k2];
                    float2 g = G[gi];
                    x2acc[i].x += dm * g.x;
                    x2acc[i].y += dm * sg * g.y;
                }
            }
        }
        wsync();
    }

    // combine 4 waves via LDS float atomics
    #pragma unroll
    for (int i = 0; i < 5; ++i) {
        int k2 = lane + 64 * i;
        if (k2 < 286) {
            atomicAdd(&sX2[k2].x, x2acc[i].x);
            atomicAdd(&sX2[k2].y, x2acc[i].y);
        }
    }
    __syncthreads();

    for (int t = tid; t < 286; t += NT) {
        float2 v = sX2[t];
        X2g[b * 5720 + t * 20 + f] =
            make_float2(v.x * (1.f / 400.f), v.y * (1.f / 400.f));
    }
}

// ---------------- stage 2a: Z half-items + Hermitian mirror ----------------
__global__ __launch_bounds__(NT) void k_Z2(
    const float2* __restrict__ X2g, const float2* __restrict__ Yk2,
    const int* __restrict__ gTABB, const int* __restrict__ gTABH,
    float2* __restrict__ Z2g) {
    const int bt = blockIdx.x & 7;        // 0..7
    const int o  = blockIdx.x >> 3;       // 0..39
    const int b0 = bt * 16;
    const int tid = threadIdx.x;

    __shared__ __align__(16) float2 sB[5792];

    const float2* Bg = Yk2 + o * 5720;
    for (int e = tid; e < 5720; e += NT) {
        int k2 = e / 20, i = e % 20;
        int p = gTABB[k2];
        int l = p & 255, r = (p >> 8) & 255, kk = p >> 16;
        sB[c_BOFF[l] + r * (40 * l + 22) + kk * 20 + i] = Bg[e];
    }
    __syncthreads();

    for (int q = tid; q < 16 * 146; q += NT) {
        int b_local = q / 146, h = q % 146;
        int ph = gTABH[h];
        int l = ph & 255, loc = ph >> 8;
        int L = 2 * l + 1;
        int mi = loc / L, ni = loc % L;
        const float4* ap = (const float4*)(X2g + (size_t)(b0 + b_local) * 5720
                                           + (c_ZB2[l] + mi * L) * 20);
        const float4* bp = (const float4*)(sB + c_BOFF[l] + ni * (40 * l + 22));
        float re = 0.f, im = 0.f;
        int n4 = 10 * L;
        for (int p4 = 0; p4 < n4; ++p4) {
            float4 a = ap[p4], y = bp[p4];
            re += a.x * y.x + a.y * y.y + a.z * y.z + a.w * y.w;
            im += a.y * y.x - a.x * y.y + a.w * y.z - a.z * y.w;
        }
        size_t base = ((size_t)(b0 + b_local) * 40 + o) * 286;
        Z2g[base + c_ZB2[l] + loc] = make_float2(re, im);
        int locm = L * L - 1 - loc;
        if (locm != loc) {
            float sg = ((mi + ni) & 1) ? -1.f : 1.f;
            Z2g[base + c_ZB2[l] + locm] = make_float2(sg * re, -sg * im);
        }
    }
}

// ---------------- stage 2b: Hermitian-halved j-loop + integrate ----------------
__global__ __launch_bounds__(NT) void k_stage2b(
    const float2* __restrict__ Z2g, const float* __restrict__ gD2R,
    const float2* __restrict__ gT12, const float2* __restrict__ gTH12,
    const float* __restrict__ gW2J, float* __restrict__ feat) {
    const int b = blockIdx.x % BT;
    const int o = blockIdx.x / BT;   // 0..39
    const int tid = threadIdx.x;
    const int wv = tid >> 6, lane = tid & 63;

    __shared__ __align__(16) float2 sZb[286];
    __shared__ __align__(16) float2 sT12[168];   // [c][n], stride 14
    __shared__ __align__(16) float2 sTH12[96];   // [a][mm], stride 8
    __shared__ __align__(16) float2 sS[4][88];   // [mm][ni] mm=0..5, stride 14
    __shared__ __align__(16) float2 sU[4][96];   // [c][mm], stride 8
    __shared__ float sredw[4];

    const float2* Zr = Z2g + ((size_t)b * 40 + o) * 286;
    for (int t = tid; t < 286; t += NT) sZb[t] = Zr[t];
    for (int t = tid; t < 132; t += NT) sT12[(t / 11) * 14 + (t % 11)] = gT12[t];
    for (int t = tid; t < 72; t += NT) sTH12[(t / 6) * 8 + (t % 6)] = gTH12[t];
    __syncthreads();

    float2* S = sS[wv];
    float2* U = sU[wv];
    float facc = 0.f;

    for (int jj = 0; jj < 3; ++jj) {
        const int j = wv + 4 * jj;

        // ---- S2[m][n], m=0..5 only
        {
            const float* dp = gD2R + j * 286;
            for (int t = lane; t < 66; t += 64) {
                int mm = t / 11, ni = t % 11;
                int n = ni - 5;
                int an = n < 0 ? -n : n;
                int lmin = mm > an ? mm : an;
                float re = 0.f, im = 0.f;
                for (int l = lmin; l < 6; ++l) {
                    int L = 2*l + 1;
                    int off = c_ZB2[l] + (mm + l) * L + (n + l);
                    float dv = dp[off];
                    float2 z = sZb[off];
                    re += dv * z.x; im += dv * z.y;
                }
                S[mm * 14 + ni] = make_float2(re, im);
            }
        }
        wsync();

        // ---- U2[m][c] = sum_n S2[m][n] T12[c][n], m=0..5; write U[c][m]
        for (int t = lane; t < 72; t += 64) {
            int mm = t / 12, c = t % 12;
            const float4* sp = (const float4*)(S + mm * 14);
            const float4* tp = (const float4*)(sT12 + c * 14);
            float re = 0.f, im = 0.f;
            #pragma unroll
            for (int p = 0; p < 5; ++p) {
                float4 s = sp[p], w = tp[p];
                re += s.x * w.x - s.y * w.y + s.z * w.z - s.w * w.w;
                im += s.x * w.y + s.y * w.x + s.z * w.w + s.w * w.z;
            }
            float2 s1 = S[mm * 14 + 10], w1 = sT12[c * 14 + 10];
            re += s1.x * w1.x - s1.y * w1.y;
            im += s1.x * w1.y + s1.y * w1.x;
            U[c * 8 + mm] = make_float2(re, im);
        }
        wsync();

        // ---- x2[a][c] = sum_{mm=0..5} Re(U2[mm][c]*TH12[a][mm]); relu; integrate
        {
            float wj = gW2J[j];
            for (int t = lane; t < 144; t += 64) {
                int a = t / 12, c = t % 12;
                const float4* up = (const float4*)(U + c * 8);
                const float4* tp = (const float4*)(sTH12 + a * 8);
                float acc = 0.f;
                #pragma unroll
                for (int p = 0; p < 3; ++p) {
                    float4 u = up[p], w = tp[p];
                    acc += u.x * w.x - u.y * w.y + u.z * w.z - u.w * w.w;
                }
                if (acc > 0.f) facc += wj * acc;
            }
        }
        wsync();
    }

    #pragma unroll
    for (int d = 32; d > 0; d >>= 1) facc += __shfl_down(facc, d, 64);
    if (lane == 0) sredw[wv] = facc;
    __syncthreads();
    if (tid == 0) {
        const float INTEG = 0.27415567780803774f;  // (2*pi/12)^2
        feat[b * 40 + o] = (sredw[0] + sredw[1] + sredw[2] + sredw[3]) * INTEG;
    }
}

__global__ void k_out(const float* __restrict__ feat, const float* __restrict__ w,
                      const float* __restrict__ bias, float* __restrict__ out) {
    int idx = blockIdx.x * blockDim.x + threadIdx.x;
    if (idx >= BT * 10) return;
    int fo = idx % 10, b = idx / 10;
    float acc = bias[fo];
    for (int o2 = 0; o2 < 40; ++o2) acc += feat[b * 40 + o2] * w[fo * 40 + o2];
    out[idx] = acc;
}

extern "C" void kernel_launch(void* const* d_in, const int* in_sizes, int n_in,
                              void* d_out, int out_size, void* d_ws, size_t ws_size,
                              hipStream_t stream) {
    (void)in_sizes; (void)n_in; (void)out_size; (void)ws_size;
    const float* x   = (const float*)d_in[0];
    const float* k1  = (const float*)d_in[1];
    const float* k2  = (const float*)d_in[2];
    const float* wO  = (const float*)d_in[3];
    const float* bO  = (const float*)d_in[4];
    float* out = (float*)d_out;

    float* ws = (float*)d_ws;
    const float2* cW60 = (const float2*)(ws + OFF_W60);
    const float*  cW2J = ws + OFF_W2J;
    const float*  cDM1 = ws + OFF_DM1;
    const float2* cY1B = (const float2*)(ws + OFF_Y1B);
    const float*  gD1R = ws + OFF_D1R;
    const float*  gDM2 = ws + OFF_DM2;
    const float2* cY2B = (const float2*)(ws + OFF_Y2B);
    const float*  gD2R = ws + OFF_D2R;
    const float2* gT19 = (const float2*)(ws + OFF_T19U);
    const float2* gT11 = (const float2*)(ws + OFF_T11V);
    const float2* gT12 = (const float2*)(ws + OFF_T12U);
    const float2* gTH19 = (const float2*)(ws + OFF_TH19);
    const float2* gTH12 = (const float2*)(ws + OFF_TH12);
    const int*    gTABB = (const int*)(ws + OFF_TABB);
    const int*    gTABH = (const int*)(ws + OFF_TABH);
    const int*    gTAH1 = (const int*)(ws + OFF_TAH1);

    float2* xh   = (float2*)(ws + OFF_END);          // 128*60*19
    float2* X    = xh + BT * 60 * 19;                // 100*128
    float2* Yk1  = X + 100 * BT;                     // 100*20
    float2* Yk2  = Yk1 + 100 * 20;                   // 40*286*20
    float2* X2   = Yk2 + 40 * 286 * 20;              // 128*286*20  [b][k2][i]
    float*  feat = (float*)(X2 + (size_t)BT * 5720); // 128*40
    float2* Z2   = (float2*)(feat + BT * 40);        // 128*40*286

    k_init<<<(N_INIT + NT - 1) / NT, NT, 0, stream>>>(ws);
    k_dft_alpha<<<(BT * 60 * 19 + NT - 1) / NT, NT, 0, stream>>>(x, cW60, xh);
    k_X1<<<(100 * BT + NT - 1) / NT, NT, 0, stream>>>(xh, cDM1, X);
    k_Yk1<<<(100 * 20 + NT - 1) / NT, NT, 0, stream>>>(k1, cY1B, Yk1);
    k_Yk2<<<146, NT, 0, stream>>>(k2, cY2B, gTABH, Yk2);
    k_stage1<<<BT * 20, NT, 0, stream>>>(X, Yk1, gD1R, gDM2, gT19, gT11, gTH19, gTAH1, gTABB, X2);
    k_Z2<<<320, NT, 0, stream>>>(X2, Yk2, gTABB, gTABH, Z2);
    k_stage2b<<<BT * 40, NT, 0, stream>>>(Z2, gD2R, gT12, gTH12, cW2J, feat);
    k_out<<<(BT * 10 + NT - 1) / NT, NT, 0, stream>>>(feat, wO, bO, out);
}